// Round 3
// baseline (1186.663 us; speedup 1.0000x reference)
//
#include <hip/hip_runtime.h>
#include <hip/hip_bf16.h>
#include <math.h>

#define B_   16384
#define S_   4
#define E_   1152
#define D_   192
#define FF_  768
#define NL_  2
#define MTOK (B_ * S_)   // 65536 tokens

typedef __attribute__((ext_vector_type(8))) _Float16 half8;
typedef __attribute__((ext_vector_type(4))) float floatx4;

__device__ __forceinline__ float gelu_f(float x) {
  return 0.5f * x * (1.0f + erff(x * 0.70710678118654752f));
}

// ---------------------------------------------------------------------------
// fp32 -> fp16 weight pre-pack (total elems % 2048 == 0)
// ---------------------------------------------------------------------------
__global__ __launch_bounds__(256) void cvt_f16_kernel(const float* __restrict__ s,
                                                      _Float16* __restrict__ d) {
  int i = (blockIdx.x * 256 + threadIdx.x) * 8;
  float4 a = *(const float4*)(s + i);
  float4 b = *(const float4*)(s + i + 4);
  half8 h;
  h[0] = (_Float16)a.x; h[1] = (_Float16)a.y; h[2] = (_Float16)a.z; h[3] = (_Float16)a.w;
  h[4] = (_Float16)b.x; h[5] = (_Float16)b.y; h[6] = (_Float16)b.z; h[7] = (_Float16)b.w;
  *(half8*)(d + i) = h;
}

// ---------------------------------------------------------------------------
// in_proj weight prep: fold input-LN into the weight.
//   Wh[n][k] = fp16(g[k] * W[n][k])
//   c1[n]    = sum_k (float)Wh[n][k]
//   c2[n]    = sum_k b[k]*W[n][k] + bias[n]
// LN(x) @ W^T + bias = rs*( x @ Wh^T - m*c1 ) + c2  per row (m, rs).
// ---------------------------------------------------------------------------
__global__ __launch_bounds__(256) void prep_inproj_w(
    const float* __restrict__ W, const float* __restrict__ g,
    const float* __restrict__ b, const float* __restrict__ bias,
    _Float16* __restrict__ Wh, float* __restrict__ c1, float* __restrict__ c2) {
  const int n = blockIdx.x * 4 + (threadIdx.x >> 6);
  const int lane = threadIdx.x & 63;
  const float* Wr = W + (size_t)n * 1152;
  _Float16* Whr = Wh + (size_t)n * 1152;
  float s1 = 0.f, s2 = 0.f;
  #pragma unroll
  for (int j = 0; j < 18; ++j) {
    int k = lane + 64 * j;
    float wv = Wr[k];
    _Float16 h = (_Float16)(wv * g[k]);
    Whr[k] = h;
    s1 += (float)h;
    s2 = fmaf(b[k], wv, s2);
  }
  #pragma unroll
  for (int off = 1; off < 64; off <<= 1) {
    s1 += __shfl_xor(s1, off);
    s2 += __shfl_xor(s2, off);
  }
  if (lane == 0) { c1[n] = s1; c2[n] = s2 + bias[n]; }
}

// ---------------------------------------------------------------------------
// in_proj: x[M,192] = posenc(GELU( rs*(emb@Wh^T - m*c1) + c2 ))
// Single streaming read of emb, LN folded into weights, B frags direct
// global->reg (L2-resident). Direct coalesced stores. BM=64, BK=64.
// ---------------------------------------------------------------------------
__global__ __launch_bounds__(256) void inproj2_kernel(
    const float* __restrict__ emb, const _Float16* __restrict__ whp,
    const float* __restrict__ c1g, const float* __restrict__ c2g,
    float* __restrict__ xout) {
  __shared__ __align__(16) _Float16 As[64][72];
  __shared__ float stats_[64][2];
  __shared__ float pe_[4][192];
  const int tid = threadIdx.x;
  const int m0 = blockIdx.x * 64;
  const int w = tid >> 6, lane = tid & 63;
  const int ln16 = lane & 15, quad = lane >> 4;
  const int r_a = tid >> 2;
  const int c_a = (tid & 3) * 16;

  for (int i = tid; i < 768; i += 256) {
    int r = i / 192, col = i - r * 192;
    float ang = (float)r * expf((float)(col & ~1) * (-0.047970522770709292f));
    pe_[r][col] = (col & 1) ? cosf(ang) : sinf(ang);
  }

  const float* Arow = emb + (size_t)(m0 + r_a) * 1152 + c_a;
  const _Float16* wb = whp + (size_t)(w * 48 + ln16) * 1152 + quad * 8;

  float4 pa[4];
  auto loadA = [&](int k0) {
    #pragma unroll
    for (int j = 0; j < 4; ++j) pa[j] = *(const float4*)(Arow + k0 + j * 4);
  };

  float s = 0.f, q = 0.f;
  floatx4 acc[4][3] = {};
  loadA(0);
  for (int k0 = 0; k0 < 1152; k0 += 64) {
    __syncthreads();
    half8 h0, h1;
    h0[0] = (_Float16)pa[0].x; h0[1] = (_Float16)pa[0].y;
    h0[2] = (_Float16)pa[0].z; h0[3] = (_Float16)pa[0].w;
    h0[4] = (_Float16)pa[1].x; h0[5] = (_Float16)pa[1].y;
    h0[6] = (_Float16)pa[1].z; h0[7] = (_Float16)pa[1].w;
    h1[0] = (_Float16)pa[2].x; h1[1] = (_Float16)pa[2].y;
    h1[2] = (_Float16)pa[2].z; h1[3] = (_Float16)pa[2].w;
    h1[4] = (_Float16)pa[3].x; h1[5] = (_Float16)pa[3].y;
    h1[6] = (_Float16)pa[3].z; h1[7] = (_Float16)pa[3].w;
    *(half8*)&As[r_a][c_a] = h0;
    *(half8*)&As[r_a][c_a + 8] = h1;
    #pragma unroll
    for (int j = 0; j < 4; ++j) {
      s += pa[j].x + pa[j].y + pa[j].z + pa[j].w;
      q = fmaf(pa[j].x, pa[j].x, q); q = fmaf(pa[j].y, pa[j].y, q);
      q = fmaf(pa[j].z, pa[j].z, q); q = fmaf(pa[j].w, pa[j].w, q);
    }
    __syncthreads();
    if (k0 + 64 < 1152) loadA(k0 + 64);
    #pragma unroll
    for (int kk = 0; kk < 64; kk += 32) {
      half8 af[4], bf[3];
      #pragma unroll
      for (int mt = 0; mt < 4; ++mt)
        af[mt] = *(const half8*)&As[mt * 16 + ln16][kk + quad * 8];
      #pragma unroll
      for (int nt = 0; nt < 3; ++nt)
        bf[nt] = *(const half8*)(wb + (size_t)nt * 16 * 1152 + k0 + kk);
      #pragma unroll
      for (int mt = 0; mt < 4; ++mt)
        #pragma unroll
        for (int nt = 0; nt < 3; ++nt)
          acc[mt][nt] = __builtin_amdgcn_mfma_f32_16x16x32_f16(
              af[mt], bf[nt], acc[mt][nt], 0, 0, 0);
    }
  }

  s += __shfl_xor(s, 1); s += __shfl_xor(s, 2);
  q += __shfl_xor(q, 1); q += __shfl_xor(q, 2);
  if ((tid & 3) == 0) {
    float mean = s * (1.f / 1152.f);
    stats_[r_a][0] = mean;
    stats_[r_a][1] = rsqrtf(q * (1.f / 1152.f) - mean * mean + 1e-5f);
  }
  __syncthreads();

  float c1v[3], c2v[3];
  #pragma unroll
  for (int nt = 0; nt < 3; ++nt) {
    c1v[nt] = c1g[w * 48 + nt * 16 + ln16];
    c2v[nt] = c2g[w * 48 + nt * 16 + ln16];
  }
  float* xg = xout + (size_t)m0 * 192;
  #pragma unroll
  for (int mt = 0; mt < 4; ++mt) {
    #pragma unroll
    for (int r = 0; r < 4; ++r) {
      const int row = mt * 16 + quad * 4 + r;
      const float rm = stats_[row][0], rr = stats_[row][1];
      #pragma unroll
      for (int nt = 0; nt < 3; ++nt) {
        const int col = w * 48 + nt * 16 + ln16;
        float v = rr * (acc[mt][nt][r] - rm * c1v[nt]) + c2v[nt];
        v = gelu_f(v);
        v += pe_[r][col];
        xg[(size_t)row * 192 + col] = v;
      }
    }
  }
}

// ---------------------------------------------------------------------------
// MEGA kernel: per 32 tokens (= 8 samples), runs BOTH transformer layers
// (attn + ff) with the residual stream held in registers, then mean-pool,
// head LN, h1/h2 (fp16 MFMA, M=8 in a 16-row tile), h3 dot -> out.
// x is read once; only out[8] is written. All weights fp16, L2-resident.
// ---------------------------------------------------------------------------
__global__ __launch_bounds__(256) void mega_kernel(
    const float* __restrict__ x,
    const _Float16* __restrict__ wqkv0, const float* __restrict__ bqkv0,
    const _Float16* __restrict__ wao0,  const float* __restrict__ bao0,
    const _Float16* __restrict__ wff10, const float* __restrict__ bff10,
    const _Float16* __restrict__ wff20, const float* __restrict__ bff20,
    const float* __restrict__ ln1g0, const float* __restrict__ ln1b0,
    const float* __restrict__ ln2g0, const float* __restrict__ ln2b0,
    const float* __restrict__ hlng, const float* __restrict__ hlnb,
    const _Float16* __restrict__ h1wh, const float* __restrict__ h1b,
    const _Float16* __restrict__ h2wh, const float* __restrict__ h2b,
    const float* __restrict__ h3w, const float* __restrict__ h3b,
    float* __restrict__ out) {
  __shared__ __align__(16) _Float16 xh[32][200];   // LN'd x / o / head ph
  __shared__ __align__(16) _Float16 qk[32][584];   // qkv / outs / ffh / head stage
  __shared__ float sp[8][4][4][4];
  const int tid = threadIdx.x;
  const int m0 = blockIdx.x * 32;
  const int w = tid >> 6, lane = tid & 63;
  const int ln16 = lane & 15, quad = lane >> 4;
  const int row = tid >> 3, cg = tid & 7;   // residual ownership
  const int ca = cg * 24;

  // load residual stream: 24 floats/thread
  float4 xr[6];
  {
    const float* Ar = x + (size_t)(m0 + row) * 192 + ca;
    #pragma unroll
    for (int j = 0; j < 6; ++j) xr[j] = *(const float4*)(Ar + j * 4);
  }

  // LN(xr) -> xh fp16 (stats via 8-thread shuffle groups)
  auto ln_to_xh = [&](const float* g, const float* bb) {
    float s = 0.f, q = 0.f;
    #pragma unroll
    for (int j = 0; j < 6; ++j) {
      float4 v = xr[j];
      s += v.x + v.y + v.z + v.w;
      q = fmaf(v.x, v.x, q); q = fmaf(v.y, v.y, q);
      q = fmaf(v.z, v.z, q); q = fmaf(v.w, v.w, q);
    }
    s += __shfl_xor(s, 1); s += __shfl_xor(s, 2); s += __shfl_xor(s, 4);
    q += __shfl_xor(q, 1); q += __shfl_xor(q, 2); q += __shfl_xor(q, 4);
    const float mean = s * (1.f / 192.f);
    const float rs = rsqrtf(q * (1.f / 192.f) - mean * mean + 1e-5f);
    #pragma unroll
    for (int j = 0; j < 3; ++j) {
      float4 a0 = xr[2 * j], a1 = xr[2 * j + 1];
      float4 g0 = *(const float4*)(g + ca + j * 8);
      float4 g1 = *(const float4*)(g + ca + j * 8 + 4);
      float4 b0 = *(const float4*)(bb + ca + j * 8);
      float4 b1 = *(const float4*)(bb + ca + j * 8 + 4);
      half8 h;
      h[0] = (_Float16)((a0.x - mean) * rs * g0.x + b0.x);
      h[1] = (_Float16)((a0.y - mean) * rs * g0.y + b0.y);
      h[2] = (_Float16)((a0.z - mean) * rs * g0.z + b0.z);
      h[3] = (_Float16)((a0.w - mean) * rs * g0.w + b0.w);
      h[4] = (_Float16)((a1.x - mean) * rs * g1.x + b1.x);
      h[5] = (_Float16)((a1.y - mean) * rs * g1.y + b1.y);
      h[6] = (_Float16)((a1.z - mean) * rs * g1.z + b1.z);
      h[7] = (_Float16)((a1.w - mean) * rs * g1.w + b1.w);
      *(half8*)&xh[row][ca + j * 8] = h;
    }
  };

  for (int l = 0; l < NL_; ++l) {
    const _Float16* wqkv = wqkv0 + (size_t)l * 110592;
    const float*    bqkv = bqkv0 + (size_t)l * 576;
    const _Float16* wao  = wao0  + (size_t)l * 36864;
    const float*    bao  = bao0  + (size_t)l * 192;
    const _Float16* wff1 = wff10 + (size_t)l * 147456;
    const float*    bff1 = bff10 + (size_t)l * 768;
    const _Float16* wff2 = wff20 + (size_t)l * 147456;
    const float*    bff2 = bff20 + (size_t)l * 192;

    // phase A: LN1 -> xh
    ln_to_xh(ln1g0 + l * 192, ln1b0 + l * 192);
    __syncthreads();

    // phase B: qkv GEMM -> qk. wave w covers cols [w*144, +144) (9 tiles)
    for (int nt = 0; nt < 9; ++nt) {
      const int nc = w * 144 + nt * 16;
      half8 bf[6];
      const _Float16* wp = wqkv + (size_t)(nc + ln16) * 192 + quad * 8;
      #pragma unroll
      for (int k = 0; k < 6; ++k) bf[k] = *(const half8*)(wp + k * 32);
      floatx4 a0v = {}, a1v = {};
      #pragma unroll
      for (int k = 0; k < 6; ++k) {
        half8 f0 = *(const half8*)&xh[ln16][k * 32 + quad * 8];
        half8 f1 = *(const half8*)&xh[16 + ln16][k * 32 + quad * 8];
        a0v = __builtin_amdgcn_mfma_f32_16x16x32_f16(f0, bf[k], a0v, 0, 0, 0);
        a1v = __builtin_amdgcn_mfma_f32_16x16x32_f16(f1, bf[k], a1v, 0, 0, 0);
      }
      const float bv = bqkv[nc + ln16];
      #pragma unroll
      for (int r = 0; r < 4; ++r) {
        qk[quad * 4 + r][nc + ln16]      = (_Float16)(a0v[r] + bv);
        qk[16 + quad * 4 + r][nc + ln16] = (_Float16)(a1v[r] + bv);
      }
    }
    __syncthreads();

    // phase C: attention. wave w handles samples 2w, 2w+1.
    #pragma unroll
    for (int s2 = 0; s2 < 2; ++s2) {
      const int sg = w * 2 + s2;
      const int hh = lane >> 4, i = (lane >> 2) & 3, j = lane & 3;
      const _Float16* qp = &qk[4 * sg + i][hh * 48];
      const _Float16* kp = &qk[4 * sg + j][192 + hh * 48];
      float s = 0.f;
      #pragma unroll
      for (int d = 0; d < 6; ++d) {
        half8 qv = *(const half8*)(qp + d * 8);
        half8 kv = *(const half8*)(kp + d * 8);
        #pragma unroll
        for (int e = 0; e < 8; ++e) s += (float)qv[e] * (float)kv[e];
      }
      s *= 0.14433756729740643f;  // 1/sqrt(48)
      float mx = fmaxf(s, __shfl_xor(s, 1));
      mx = fmaxf(mx, __shfl_xor(mx, 2));
      float e = expf(s - mx);
      float sum = e + __shfl_xor(e, 1);
      sum += __shfl_xor(sum, 2);
      sp[sg][hh][i][j] = e / sum;
    }
    #pragma unroll
    for (int s2 = 0; s2 < 2; ++s2) {
      const int sg = w * 2 + s2;
      #pragma unroll
      for (int ii = 0; ii < 4; ++ii) {
        #pragma unroll
        for (int cc = 0; cc < 3; ++cc) {
          const int c = lane + cc * 64;
          const int hh = c / 48;
          float a = 0.f;
          #pragma unroll
          for (int jj = 0; jj < 4; ++jj)
            a += sp[sg][hh][ii][jj] * (float)qk[4 * sg + jj][384 + c];
          xh[4 * sg + ii][c] = (_Float16)a;
        }
      }
    }
    __syncthreads();

    // phase D: attn_out GEMM -> outs (fp32 in qk region)
    float* outs = (float*)&qk[0][0];
    #pragma unroll
    for (int nt = 0; nt < 3; ++nt) {
      const int nc = w * 48 + nt * 16;
      half8 bf[6];
      const _Float16* wp = wao + (size_t)(nc + ln16) * 192 + quad * 8;
      #pragma unroll
      for (int k = 0; k < 6; ++k) bf[k] = *(const half8*)(wp + k * 32);
      floatx4 a0v = {}, a1v = {};
      #pragma unroll
      for (int k = 0; k < 6; ++k) {
        half8 f0 = *(const half8*)&xh[ln16][k * 32 + quad * 8];
        half8 f1 = *(const half8*)&xh[16 + ln16][k * 32 + quad * 8];
        a0v = __builtin_amdgcn_mfma_f32_16x16x32_f16(f0, bf[k], a0v, 0, 0, 0);
        a1v = __builtin_amdgcn_mfma_f32_16x16x32_f16(f1, bf[k], a1v, 0, 0, 0);
      }
      const float bv = bao[nc + ln16];
      #pragma unroll
      for (int r = 0; r < 4; ++r) {
        outs[(quad * 4 + r) * 192 + nc + ln16]      = a0v[r] + bv;
        outs[(16 + quad * 4 + r) * 192 + nc + ln16] = a1v[r] + bv;
      }
    }
    __syncthreads();

    // phase E: residual += attn_out; LN2 -> xh
    {
      const float* os = (const float*)&qk[0][0] + row * 192 + ca;
      #pragma unroll
      for (int j = 0; j < 6; ++j) {
        float4 o4 = *(const float4*)(os + j * 4);
        xr[j].x += o4.x; xr[j].y += o4.y; xr[j].z += o4.z; xr[j].w += o4.w;
      }
    }
    ln_to_xh(ln2g0 + l * 192, ln2b0 + l * 192);
    __syncthreads();

    // phase F: FF. intermediate 768 in two halves of 384; acc2 in regs.
    floatx4 acc2[2][3] = {};
    _Float16 (*ffh)[392] = (_Float16 (*)[392])&qk[0][0];
    for (int hf = 0; hf < 2; ++hf) {
      #pragma unroll
      for (int nt = 0; nt < 6; ++nt) {
        const int ng = hf * 384 + w * 96 + nt * 16;
        const int nl = w * 96 + nt * 16;
        half8 bf[6];
        const _Float16* wp = wff1 + (size_t)(ng + ln16) * 192 + quad * 8;
        #pragma unroll
        for (int k = 0; k < 6; ++k) bf[k] = *(const half8*)(wp + k * 32);
        floatx4 a4[2] = {};
        #pragma unroll
        for (int k = 0; k < 6; ++k) {
          #pragma unroll
          for (int mt = 0; mt < 2; ++mt) {
            half8 af = *(const half8*)&xh[mt * 16 + ln16][k * 32 + quad * 8];
            a4[mt] = __builtin_amdgcn_mfma_f32_16x16x32_f16(af, bf[k], a4[mt], 0, 0, 0);
          }
        }
        const float bv = bff1[ng + ln16];
        #pragma unroll
        for (int mt = 0; mt < 2; ++mt)
          #pragma unroll
          for (int r = 0; r < 4; ++r)
            ffh[mt * 16 + quad * 4 + r][nl + ln16] = (_Float16)gelu_f(a4[mt][r] + bv);
      }
      __syncthreads();
      for (int k12 = 0; k12 < 12; ++k12) {
        half8 af[2];
        #pragma unroll
        for (int mt = 0; mt < 2; ++mt)
          af[mt] = *(const half8*)&ffh[mt * 16 + ln16][k12 * 32 + quad * 8];
        #pragma unroll
        for (int nt = 0; nt < 3; ++nt) {
          const int nc = w * 48 + nt * 16;
          half8 bf = *(const half8*)(wff2 + (size_t)(nc + ln16) * 768 +
                                     hf * 384 + k12 * 32 + quad * 8);
          #pragma unroll
          for (int mt = 0; mt < 2; ++mt)
            acc2[mt][nt] = __builtin_amdgcn_mfma_f32_16x16x32_f16(
                af[mt], bf, acc2[mt][nt], 0, 0, 0);
        }
      }
      __syncthreads();
    }
    // stage ff2 result
    {
      float* outs2 = (float*)&qk[0][0];
      #pragma unroll
      for (int nt = 0; nt < 3; ++nt) {
        const int nc = w * 48 + nt * 16;
        const float bv = bff2[nc + ln16];
        #pragma unroll
        for (int mt = 0; mt < 2; ++mt)
          #pragma unroll
          for (int r = 0; r < 4; ++r)
            outs2[(mt * 16 + quad * 4 + r) * 192 + nc + ln16] = acc2[mt][nt][r] + bv;
      }
    }
    __syncthreads();
    // residual += ff_out
    {
      const float* os = (const float*)&qk[0][0] + row * 192 + ca;
      #pragma unroll
      for (int j = 0; j < 6; ++j) {
        float4 o4 = *(const float4*)(os + j * 4);
        xr[j].x += o4.x; xr[j].y += o4.y; xr[j].z += o4.z; xr[j].w += o4.w;
      }
    }
    __syncthreads();   // outs reads done before next-layer qk writes
  }

  // ---- head: pool + LN + h1 + h2 + h3 ----
  // stage final x fp32 into qk region
  {
    float* xs = (float*)&qk[0][0];
    #pragma unroll
    for (int j = 0; j < 6; ++j)
      *(float4*)(xs + row * 192 + ca + j * 4) = xr[j];
  }
  __syncthreads();
  // pooled + head LN -> ph16 (xh region), rows 8..15 zeroed
  _Float16 (*ph)[200] = (_Float16 (*)[200])&xh[0][0];
  {
    const float* xs = (const float*)&qk[0][0];
    const int s = tid >> 5, u = tid & 31;
    float pv[6];
    float ss = 0.f, qq = 0.f;
    #pragma unroll
    for (int c6 = 0; c6 < 6; ++c6) {
      const int c = u * 6 + c6;
      float v = 0.25f * (xs[(4 * s) * 192 + c] + xs[(4 * s + 1) * 192 + c] +
                         xs[(4 * s + 2) * 192 + c] + xs[(4 * s + 3) * 192 + c]);
      pv[c6] = v; ss += v; qq = fmaf(v, v, qq);
    }
    ss += __shfl_xor(ss, 1); ss += __shfl_xor(ss, 2); ss += __shfl_xor(ss, 4);
    ss += __shfl_xor(ss, 8); ss += __shfl_xor(ss, 16);
    qq += __shfl_xor(qq, 1); qq += __shfl_xor(qq, 2); qq += __shfl_xor(qq, 4);
    qq += __shfl_xor(qq, 8); qq += __shfl_xor(qq, 16);
    const float mean = ss * (1.f / 192.f);
    const float rs = rsqrtf(qq * (1.f / 192.f) - mean * mean + 1e-5f);
    #pragma unroll
    for (int c6 = 0; c6 < 6; ++c6) {
      const int c = u * 6 + c6;
      ph[s][c] = (_Float16)((pv[c6] - mean) * rs * hlng[c] + hlnb[c]);
      ph[8 + s][c] = (_Float16)0.f;
    }
  }
  __syncthreads();
  // h1: [8x192] @ [256x192]^T -> h1s fp16 (rows 8..15 zero). 16 tiles, 4/wave.
  _Float16 (*h1s)[264] = (_Float16 (*)[264])&qk[0][0];   // 16*264*2 = 8448 B
  #pragma unroll
  for (int nt = 0; nt < 4; ++nt) {
    const int nc = w * 64 + nt * 16;
    half8 bf[6];
    const _Float16* wp = h1wh + (size_t)(nc + ln16) * 192 + quad * 8;
    #pragma unroll
    for (int k = 0; k < 6; ++k) bf[k] = *(const half8*)(wp + k * 32);
    floatx4 a4 = {};
    #pragma unroll
    for (int k = 0; k < 6; ++k) {
      half8 af = *(const half8*)&ph[ln16][k * 32 + quad * 8];
      a4 = __builtin_amdgcn_mfma_f32_16x16x32_f16(af, bf[k], a4, 0, 0, 0);
    }
    const float bv = h1b[nc + ln16];
    #pragma unroll
    for (int r = 0; r < 4; ++r) {
      const int rr = quad * 4 + r;
      h1s[rr][nc + ln16] = (rr < 8) ? (_Float16)gelu_f(a4[r] + bv) : (_Float16)0.f;
    }
  }
  __syncthreads();
  // h2: [8x256] @ [64x256]^T -> h2s fp16. 4 tiles, 1/wave, K=256.
  _Float16 (*h2s)[72] = (_Float16 (*)[72])((char*)&qk[0][0] + 16384);
  {
    const int nc = w * 16;
    floatx4 a4 = {};
    #pragma unroll
    for (int k = 0; k < 8; ++k) {
      half8 af = *(const half8*)&h1s[ln16][k * 32 + quad * 8];
      half8 bf = *(const half8*)(h2wh + (size_t)(nc + ln16) * 256 + k * 32 + quad * 8);
      a4 = __builtin_amdgcn_mfma_f32_16x16x32_f16(af, bf, a4, 0, 0, 0);
    }
    const float bv = h2b[nc + ln16];
    #pragma unroll
    for (int r = 0; r < 4; ++r) {
      const int rr = quad * 4 + r;
      if (rr < 8) h2s[rr][nc + ln16] = (_Float16)gelu_f(a4[r] + bv);
    }
  }
  __syncthreads();
  // h3: out[sample] = h2s[s][:64] . h3w + h3b  (32 threads/sample)
  {
    const int s = tid >> 5, u = tid & 31;
    float v = (float)h2s[s][2 * u] * h3w[2 * u] +
              (float)h2s[s][2 * u + 1] * h3w[2 * u + 1];
    v += __shfl_xor(v, 1); v += __shfl_xor(v, 2); v += __shfl_xor(v, 4);
    v += __shfl_xor(v, 8); v += __shfl_xor(v, 16);
    if (u == 0) out[blockIdx.x * 8 + s] = v + h3b[0];
  }
}

// ---------------------------------------------------------------------------
extern "C" void kernel_launch(void* const* d_in, const int* in_sizes, int n_in,
                              void* d_out, int out_size, void* d_ws, size_t ws_size,
                              hipStream_t stream) {
  (void)in_sizes; (void)n_in; (void)out_size; (void)ws_size;
  const float* emb       = (const float*)d_in[0];
  const float* in_ln_w   = (const float*)d_in[1];
  const float* in_ln_b   = (const float*)d_in[2];
  const float* in_proj_w = (const float*)d_in[3];
  const float* in_proj_b = (const float*)d_in[4];
  const float* qkv_w     = (const float*)d_in[5];
  const float* qkv_b     = (const float*)d_in[6];
  const float* aow       = (const float*)d_in[7];
  const float* aob       = (const float*)d_in[8];
  const float* ln1w      = (const float*)d_in[9];
  const float* ln1b      = (const float*)d_in[10];
  const float* ln2w      = (const float*)d_in[11];
  const float* ln2b      = (const float*)d_in[12];
  const float* ff1w      = (const float*)d_in[13];
  const float* ff1b      = (const float*)d_in[14];
  const float* ff2w      = (const float*)d_in[15];
  const float* ff2b      = (const float*)d_in[16];
  const float* hlnw      = (const float*)d_in[17];
  const float* hlnb      = (const float*)d_in[18];
  const float* h1w       = (const float*)d_in[19];
  const float* h1b       = (const float*)d_in[20];
  const float* h2w       = (const float*)d_in[21];
  const float* h2b       = (const float*)d_in[22];
  const float* h3w       = (const float*)d_in[23];
  const float* h3b       = (const float*)d_in[24];
  float* out = (float*)d_out;

  float* ws = (float*)d_ws;
  size_t off = 0;
  float* x   = ws + off; off += (size_t)MTOK * D_;   // fp32 residual stream
  float* c1  = ws + off; off += 192;                 // in_proj LN-fold consts
  float* c2  = ws + off; off += 192;
  // fp16 weight pack region
  _Float16* wh = (_Float16*)(ws + off);
  _Float16* w_inproj = wh;                       // 192*1152  = 221184
  _Float16* w_qkv    = w_inproj + 221184;        // 2*576*192 = 221184
  _Float16* w_ao     = w_qkv    + 221184;        // 2*192*192 =  73728
  _Float16* w_ff1    = w_ao     + 73728;         // 2*768*192 = 294912
  _Float16* w_ff2    = w_ff1    + 294912;        // 2*192*768 = 294912
  _Float16* w_h1     = w_ff2    + 294912;        // 256*192   =  49152
  _Float16* w_h2     = w_h1     + 49152;         // 64*256    =  16384

  prep_inproj_w<<<48, 256, 0, stream>>>(in_proj_w, in_ln_w, in_ln_b, in_proj_b,
                                        w_inproj, c1, c2);
  cvt_f16_kernel<<<221184 / 2048, 256, 0, stream>>>(qkv_w, w_qkv);
  cvt_f16_kernel<<<73728  / 2048, 256, 0, stream>>>(aow, w_ao);
  cvt_f16_kernel<<<294912 / 2048, 256, 0, stream>>>(ff1w, w_ff1);
  cvt_f16_kernel<<<294912 / 2048, 256, 0, stream>>>(ff2w, w_ff2);
  cvt_f16_kernel<<<49152  / 2048, 256, 0, stream>>>(h1w, w_h1);
  cvt_f16_kernel<<<16384  / 2048, 256, 0, stream>>>(h2w, w_h2);

  inproj2_kernel<<<MTOK / 64, 256, 0, stream>>>(emb, w_inproj, c1, c2, x);

  mega_kernel<<<MTOK / 32, 256, 0, stream>>>(
      x, w_qkv, qkv_b, w_ao, aob, w_ff1, ff1b, w_ff2, ff2b,
      ln1w, ln1b, ln2w, ln2b, hlnw, hlnb,
      w_h1, h1b, w_h2, h2b, h3w, h3b, out);
}

// Round 6
// 998.511 us; speedup vs baseline: 1.1884x; 1.1884x over previous
//
#include <hip/hip_runtime.h>
#include <hip/hip_bf16.h>
#include <math.h>

#define B_   16384
#define S_   4
#define E_   1152
#define D_   192
#define FF_  768
#define NL_  2
#define MTOK (B_ * S_)   // 65536 tokens

typedef __attribute__((ext_vector_type(8))) _Float16 half8;
typedef __attribute__((ext_vector_type(4))) float floatx4;

__device__ __forceinline__ float gelu_f(float x) {
  return 0.5f * x * (1.0f + erff(x * 0.70710678118654752f));
}

// ---------------------------------------------------------------------------
// fp32 -> fp16 weight pre-pack (total elems % 2048 == 0)
// ---------------------------------------------------------------------------
__global__ __launch_bounds__(256) void cvt_f16_kernel(const float* __restrict__ s,
                                                      _Float16* __restrict__ d) {
  int i = (blockIdx.x * 256 + threadIdx.x) * 8;
  float4 a = *(const float4*)(s + i);
  float4 b = *(const float4*)(s + i + 4);
  half8 h;
  h[0] = (_Float16)a.x; h[1] = (_Float16)a.y; h[2] = (_Float16)a.z; h[3] = (_Float16)a.w;
  h[4] = (_Float16)b.x; h[5] = (_Float16)b.y; h[6] = (_Float16)b.z; h[7] = (_Float16)b.w;
  *(half8*)(d + i) = h;
}

// ---------------------------------------------------------------------------
// in_proj weight prep: fold input-LN into the weight.
//   Wh[n][k] = fp16(g[k] * W[n][k])
//   c1[n]    = sum_k (float)Wh[n][k]
//   c2[n]    = sum_k b[k]*W[n][k] + bias[n]
// LN(x) @ W^T + bias = rs*( x @ Wh^T - m*c1 ) + c2  per row (m, rs).
// ---------------------------------------------------------------------------
__global__ __launch_bounds__(256) void prep_inproj_w(
    const float* __restrict__ W, const float* __restrict__ g,
    const float* __restrict__ b, const float* __restrict__ bias,
    _Float16* __restrict__ Wh, float* __restrict__ c1, float* __restrict__ c2) {
  const int n = blockIdx.x * 4 + (threadIdx.x >> 6);
  const int lane = threadIdx.x & 63;
  const float* Wr = W + (size_t)n * 1152;
  _Float16* Whr = Wh + (size_t)n * 1152;
  float s1 = 0.f, s2 = 0.f;
  #pragma unroll
  for (int j = 0; j < 18; ++j) {
    int k = lane + 64 * j;
    float wv = Wr[k];
    _Float16 h = (_Float16)(wv * g[k]);
    Whr[k] = h;
    s1 += (float)h;
    s2 = fmaf(b[k], wv, s2);
  }
  #pragma unroll
  for (int off = 1; off < 64; off <<= 1) {
    s1 += __shfl_xor(s1, off);
    s2 += __shfl_xor(s2, off);
  }
  if (lane == 0) { c1[n] = s1; c2[n] = s2 + bias[n]; }
}

// ---------------------------------------------------------------------------
// in_proj v2: x[M,192] = posenc(GELU( rs*(emb@Wh^T - m*c1) + c2 ))
// Single streaming read of emb (fp32), LN folded into weights (prep kernel),
// row stats (m, rs) accumulated on the fly. B fragments loaded direct
// global->reg (W is L2-resident, 442 KB). No fp32 output staging: direct
// 64B-coalesced stores + shuffle-reduced output LN1 stats into stD.
// BM=64, BK=64, 4 waves (wave w owns cols [48w, 48w+48)).
// ---------------------------------------------------------------------------
__global__ __launch_bounds__(256) void inproj2_kernel(
    const float* __restrict__ emb, const _Float16* __restrict__ whp,
    const float* __restrict__ c1g, const float* __restrict__ c2g,
    float* __restrict__ xout, float* __restrict__ stD) {
  __shared__ __align__(16) _Float16 As[64][72];   // padded: conflict-free frags
  __shared__ float stats_[64][2];                 // emb-row (mean, rstd)
  __shared__ float red_[4][64][2];                // per-wave output-stat partials
  __shared__ float pe_[4][192];                   // posenc table
  const int tid = threadIdx.x;
  const int m0 = blockIdx.x * 64;
  const int w = tid >> 6, lane = tid & 63;
  const int ln16 = lane & 15, quad = lane >> 4;
  const int r_a = tid >> 2;            // 0..63 (A-stage row)
  const int c_a = (tid & 3) * 16;      // 0/16/32/48 within BK=64

  // posenc table (768 entries, 3 per thread)
  for (int i = tid; i < 768; i += 256) {
    int r = i / 192, col = i - r * 192;
    float ang = (float)r * expf((float)(col & ~1) * (-0.047970522770709292f));
    pe_[r][col] = (col & 1) ? cosf(ang) : sinf(ang);
  }

  const float* Arow = emb + (size_t)(m0 + r_a) * 1152 + c_a;
  const _Float16* wb = whp + (size_t)(w * 48 + ln16) * 1152 + quad * 8;

  float4 pa[4];
  auto loadA = [&](int k0) {
    #pragma unroll
    for (int j = 0; j < 4; ++j) pa[j] = *(const float4*)(Arow + k0 + j * 4);
  };

  float s = 0.f, q = 0.f;
  floatx4 acc[4][3] = {};
  loadA(0);
  for (int k0 = 0; k0 < 1152; k0 += 64) {
    __syncthreads();   // prior-iter fragment reads of As complete
    half8 h0, h1;
    h0[0] = (_Float16)pa[0].x; h0[1] = (_Float16)pa[0].y;
    h0[2] = (_Float16)pa[0].z; h0[3] = (_Float16)pa[0].w;
    h0[4] = (_Float16)pa[1].x; h0[5] = (_Float16)pa[1].y;
    h0[6] = (_Float16)pa[1].z; h0[7] = (_Float16)pa[1].w;
    h1[0] = (_Float16)pa[2].x; h1[1] = (_Float16)pa[2].y;
    h1[2] = (_Float16)pa[2].z; h1[3] = (_Float16)pa[2].w;
    h1[4] = (_Float16)pa[3].x; h1[5] = (_Float16)pa[3].y;
    h1[6] = (_Float16)pa[3].z; h1[7] = (_Float16)pa[3].w;
    *(half8*)&As[r_a][c_a] = h0;
    *(half8*)&As[r_a][c_a + 8] = h1;
    #pragma unroll
    for (int j = 0; j < 4; ++j) {
      s += pa[j].x + pa[j].y + pa[j].z + pa[j].w;
      q = fmaf(pa[j].x, pa[j].x, q); q = fmaf(pa[j].y, pa[j].y, q);
      q = fmaf(pa[j].z, pa[j].z, q); q = fmaf(pa[j].w, pa[j].w, q);
    }
    __syncthreads();   // As visible
    if (k0 + 64 < 1152) loadA(k0 + 64);   // prefetch overlaps compute below
    #pragma unroll
    for (int kk = 0; kk < 64; kk += 32) {
      half8 af[4], bf[3];
      #pragma unroll
      for (int mt = 0; mt < 4; ++mt)
        af[mt] = *(const half8*)&As[mt * 16 + ln16][kk + quad * 8];
      #pragma unroll
      for (int nt = 0; nt < 3; ++nt)
        bf[nt] = *(const half8*)(wb + (size_t)nt * 16 * 1152 + k0 + kk);
      #pragma unroll
      for (int mt = 0; mt < 4; ++mt)
        #pragma unroll
        for (int nt = 0; nt < 3; ++nt)
          acc[mt][nt] = __builtin_amdgcn_mfma_f32_16x16x32_f16(
              af[mt], bf[nt], acc[mt][nt], 0, 0, 0);
    }
  }

  // finalize emb-row LN stats (4 threads per row)
  s += __shfl_xor(s, 1); s += __shfl_xor(s, 2);
  q += __shfl_xor(q, 1); q += __shfl_xor(q, 2);
  if ((tid & 3) == 0) {
    float mean = s * (1.f / 1152.f);
    stats_[r_a][0] = mean;
    stats_[r_a][1] = rsqrtf(q * (1.f / 1152.f) - mean * mean + 1e-5f);
  }
  __syncthreads();

  // epilogue: correction + GELU + posenc, direct coalesced stores,
  // fused output LN1 stats (16-lane shuffle reduce -> LDS -> combine)
  float c1v[3], c2v[3];
  #pragma unroll
  for (int nt = 0; nt < 3; ++nt) {
    c1v[nt] = c1g[w * 48 + nt * 16 + ln16];
    c2v[nt] = c2g[w * 48 + nt * 16 + ln16];
  }
  float* xg = xout + (size_t)m0 * 192;
  #pragma unroll
  for (int mt = 0; mt < 4; ++mt) {
    #pragma unroll
    for (int r = 0; r < 4; ++r) {
      const int row = mt * 16 + quad * 4 + r;   // (global row)&3 == r
      const float rm = stats_[row][0], rr = stats_[row][1];
      float so = 0.f, qo = 0.f;
      #pragma unroll
      for (int nt = 0; nt < 3; ++nt) {
        const int col = w * 48 + nt * 16 + ln16;
        float v = rr * (acc[mt][nt][r] - rm * c1v[nt]) + c2v[nt];
        v = gelu_f(v);
        v += pe_[r][col];
        xg[(size_t)row * 192 + col] = v;
        so += v;
        qo = fmaf(v, v, qo);
      }
      so += __shfl_xor(so, 1); so += __shfl_xor(so, 2);
      so += __shfl_xor(so, 4); so += __shfl_xor(so, 8);
      qo += __shfl_xor(qo, 1); qo += __shfl_xor(qo, 2);
      qo += __shfl_xor(qo, 4); qo += __shfl_xor(qo, 8);
      if (ln16 == 0) { red_[w][row][0] = so; red_[w][row][1] = qo; }
    }
  }
  __syncthreads();
  if (tid < 64) {
    float so = red_[0][tid][0] + red_[1][tid][0] + red_[2][tid][0] + red_[3][tid][0];
    float qo = red_[0][tid][1] + red_[1][tid][1] + red_[2][tid][1] + red_[3][tid][1];
    float mean = so * (1.f / 192.f);
    stD[2 * (m0 + tid)] = mean;
    stD[2 * (m0 + tid) + 1] = rsqrtf(qo * (1.f / 192.f) - mean * mean + 1e-5f);
  }
}

// ---------------------------------------------------------------------------
// Fused attention block (per layer): x += attn_out(attn(qkv(LN1(x))))
// BM=32 tokens = 8 samples/block. B-fragments loaded directly global->reg
// from fp16 W[n][k]. qkv + o never touch HBM. Writes LN2 stats into stD.
// ---------------------------------------------------------------------------
__global__ __launch_bounds__(256) void layer_attn_kernel(
    float* __restrict__ x, const _Float16* __restrict__ wqkv,
    const float* __restrict__ bqkv, const _Float16* __restrict__ wao,
    const float* __restrict__ bao, const float* __restrict__ ln1g,
    const float* __restrict__ ln1b_, float* __restrict__ stD) {
  __shared__ __align__(16) _Float16 xh[32][200];   // LN1(x), then o
  __shared__ __align__(16) _Float16 qk[32][584];   // qkv, then fp32 out stage
  __shared__ float sp[8][4][4][4];
  const int tid = threadIdx.x;
  const int m0 = blockIdx.x * 32;
  const int w = tid >> 6, lane = tid & 63;
  const int ln16 = lane & 15, quad = lane >> 4;

  // phase 0: LN1(x) -> xh (8 threads per row, 24 floats each)
  {
    const int ra = tid >> 3, ca = (tid & 7) * 24;
    const float sm = stD[2 * (m0 + ra)], srs = stD[2 * (m0 + ra) + 1];
    const float* Ar = x + (size_t)(m0 + ra) * 192 + ca;
    #pragma unroll
    for (int j = 0; j < 3; ++j) {
      float4 a0 = *(const float4*)(Ar + j * 8);
      float4 a1 = *(const float4*)(Ar + j * 8 + 4);
      float4 g0 = *(const float4*)(ln1g + ca + j * 8);
      float4 g1 = *(const float4*)(ln1g + ca + j * 8 + 4);
      float4 b0 = *(const float4*)(ln1b_ + ca + j * 8);
      float4 b1 = *(const float4*)(ln1b_ + ca + j * 8 + 4);
      half8 h;
      h[0] = (_Float16)((a0.x - sm) * srs * g0.x + b0.x);
      h[1] = (_Float16)((a0.y - sm) * srs * g0.y + b0.y);
      h[2] = (_Float16)((a0.z - sm) * srs * g0.z + b0.z);
      h[3] = (_Float16)((a0.w - sm) * srs * g0.w + b0.w);
      h[4] = (_Float16)((a1.x - sm) * srs * g1.x + b1.x);
      h[5] = (_Float16)((a1.y - sm) * srs * g1.y + b1.y);
      h[6] = (_Float16)((a1.z - sm) * srs * g1.z + b1.z);
      h[7] = (_Float16)((a1.w - sm) * srs * g1.w + b1.w);
      *(half8*)&xh[ra][ca + j * 8] = h;
    }
  }
  __syncthreads();

  // phase 1: qkv -> qk LDS. wave w covers cols [w*144, w*144+144) (9 tiles)
  for (int nt = 0; nt < 9; ++nt) {
    const int nc = w * 144 + nt * 16;
    half8 bf[6];
    const _Float16* wp = wqkv + (size_t)(nc + ln16) * 192 + quad * 8;
    #pragma unroll
    for (int k = 0; k < 6; ++k) bf[k] = *(const half8*)(wp + k * 32);
    floatx4 a0v = {}, a1v = {};
    #pragma unroll
    for (int k = 0; k < 6; ++k) {
      half8 f0 = *(const half8*)&xh[ln16][k * 32 + quad * 8];
      half8 f1 = *(const half8*)&xh[16 + ln16][k * 32 + quad * 8];
      a0v = __builtin_amdgcn_mfma_f32_16x16x32_f16(f0, bf[k], a0v, 0, 0, 0);
      a1v = __builtin_amdgcn_mfma_f32_16x16x32_f16(f1, bf[k], a1v, 0, 0, 0);
    }
    const float bv = bqkv[nc + ln16];
    #pragma unroll
    for (int r = 0; r < 4; ++r) {
      qk[quad * 4 + r][nc + ln16]      = (_Float16)(a0v[r] + bv);
      qk[16 + quad * 4 + r][nc + ln16] = (_Float16)(a1v[r] + bv);
    }
  }
  __syncthreads();

  // phase 2: attention. wave w handles samples 2w, 2w+1 (rows 4sg..4sg+3).
  #pragma unroll
  for (int s2 = 0; s2 < 2; ++s2) {
    const int sg = w * 2 + s2;
    const int h = lane >> 4, i = (lane >> 2) & 3, j = lane & 3;
    const _Float16* qp = &qk[4 * sg + i][h * 48];
    const _Float16* kp = &qk[4 * sg + j][192 + h * 48];
    float s = 0.f;
    #pragma unroll
    for (int d = 0; d < 6; ++d) {
      half8 qv = *(const half8*)(qp + d * 8);
      half8 kv = *(const half8*)(kp + d * 8);
      #pragma unroll
      for (int e = 0; e < 8; ++e) s += (float)qv[e] * (float)kv[e];
    }
    s *= 0.14433756729740643f;  // 1/sqrt(48)
    float mx = fmaxf(s, __shfl_xor(s, 1));
    mx = fmaxf(mx, __shfl_xor(mx, 2));
    float e = expf(s - mx);
    float sum = e + __shfl_xor(e, 1);
    sum += __shfl_xor(sum, 2);
    sp[sg][h][i][j] = e / sum;   // wave-local; same wave reads below
  }
  #pragma unroll
  for (int s2 = 0; s2 < 2; ++s2) {
    const int sg = w * 2 + s2;
    #pragma unroll
    for (int ii = 0; ii < 4; ++ii) {
      #pragma unroll
      for (int cc = 0; cc < 3; ++cc) {
        const int c = lane + cc * 64;
        const int hh = c / 48;
        float a = 0.f;
        #pragma unroll
        for (int jj = 0; jj < 4; ++jj)
          a += sp[sg][hh][ii][jj] * (float)qk[4 * sg + jj][384 + c];
        xh[4 * sg + ii][c] = (_Float16)a;   // o overwrites LN1 tile (reads done)
      }
    }
  }
  __syncthreads();

  // phase 3: attn_out GEMM. wave w cols [w*48, w*48+48).
  float* outs = (float*)&qk[0][0];   // 32*192*4 = 24576 B <= 37376 B
  #pragma unroll
  for (int nt = 0; nt < 3; ++nt) {
    const int nc = w * 48 + nt * 16;
    half8 bf[6];
    const _Float16* wp = wao + (size_t)(nc + ln16) * 192 + quad * 8;
    #pragma unroll
    for (int k = 0; k < 6; ++k) bf[k] = *(const half8*)(wp + k * 32);
    floatx4 a0v = {}, a1v = {};
    #pragma unroll
    for (int k = 0; k < 6; ++k) {
      half8 f0 = *(const half8*)&xh[ln16][k * 32 + quad * 8];
      half8 f1 = *(const half8*)&xh[16 + ln16][k * 32 + quad * 8];
      a0v = __builtin_amdgcn_mfma_f32_16x16x32_f16(f0, bf[k], a0v, 0, 0, 0);
      a1v = __builtin_amdgcn_mfma_f32_16x16x32_f16(f1, bf[k], a1v, 0, 0, 0);
    }
    const float bv = bao[nc + ln16];
    #pragma unroll
    for (int r = 0; r < 4; ++r) {
      outs[(quad * 4 + r) * 192 + nc + ln16]      = a0v[r] + bv;
      outs[(16 + quad * 4 + r) * 192 + nc + ln16] = a1v[r] + bv;
    }
  }
  __syncthreads();

  // phase 4: coalesced residual add + write + LN2 stats (8 threads per row)
  {
    const int fbase = tid * 6;      // 1536 float4 total
    const int row = tid >> 3;
    float* xg = x + (size_t)m0 * 192;
    float s = 0.f, q = 0.f;
    #pragma unroll
    for (int j = 0; j < 6; ++j) {
      float4 v = ((const float4*)outs)[fbase + j];
      float4 rr = *(const float4*)(xg + (fbase + j) * 4);
      v.x += rr.x; v.y += rr.y; v.z += rr.z; v.w += rr.w;
      s += v.x + v.y + v.z + v.w;
      q += v.x * v.x + v.y * v.y + v.z * v.z + v.w * v.w;
      *(float4*)(xg + (fbase + j) * 4) = v;
    }
    s += __shfl_xor(s, 1); s += __shfl_xor(s, 2); s += __shfl_xor(s, 4);
    q += __shfl_xor(q, 1); q += __shfl_xor(q, 2); q += __shfl_xor(q, 4);
    if ((tid & 7) == 0) {
      float mean = s * (1.f / 192.f);
      stD[2 * (m0 + row)] = mean;
      stD[2 * (m0 + row) + 1] = rsqrtf(q * (1.f / 192.f) - mean * mean + 1e-5f);
    }
  }
}

// ---------------------------------------------------------------------------
// Fused FF block (per layer): x += ff2(GELU(ff1(LN2(x))))
// BM=64. FF intermediate (768) computed in FOUR 192-col quarters held in LDS
// (51.2 KB total -> 3 blocks/CU); ff2 accumulates across quarters in regs.
// Identical MFMA sequence/order to the proven halves version. Writes
// next-LN1 stats.
// ---------------------------------------------------------------------------
__global__ __launch_bounds__(256) void layer_ff_kernel(
    float* __restrict__ x, const _Float16* __restrict__ wff1,
    const float* __restrict__ bff1, const _Float16* __restrict__ wff2,
    const float* __restrict__ bff2, const float* __restrict__ ln2g,
    const float* __restrict__ ln2b_, float* __restrict__ stD) {
  __shared__ __align__(16) char pool[51200];
  _Float16 (*xh2)[200] = (_Float16 (*)[200])pool;            // LN2(x)  [0,25600)
  _Float16 (*ffh)[200] = (_Float16 (*)[200])(pool + 25600);  // FF qtr [25600,51200)
  const int tid = threadIdx.x;
  const int m0 = blockIdx.x * 64;
  const int w = tid >> 6, lane = tid & 63;
  const int ln16 = lane & 15, quad = lane >> 4;

  // phase 0: LN2(x) -> xh2 (4 threads per row, 48 floats each)
  {
    const int ra = tid >> 2, ca = (tid & 3) * 48;
    const float sm = stD[2 * (m0 + ra)], srs = stD[2 * (m0 + ra) + 1];
    const float* Ar = x + (size_t)(m0 + ra) * 192 + ca;
    #pragma unroll
    for (int j = 0; j < 6; ++j) {
      float4 a0 = *(const float4*)(Ar + j * 8);
      float4 a1 = *(const float4*)(Ar + j * 8 + 4);
      float4 g0 = *(const float4*)(ln2g + ca + j * 8);
      float4 g1 = *(const float4*)(ln2g + ca + j * 8 + 4);
      float4 b0 = *(const float4*)(ln2b_ + ca + j * 8);
      float4 b1 = *(const float4*)(ln2b_ + ca + j * 8 + 4);
      half8 h;
      h[0] = (_Float16)((a0.x - sm) * srs * g0.x + b0.x);
      h[1] = (_Float16)((a0.y - sm) * srs * g0.y + b0.y);
      h[2] = (_Float16)((a0.z - sm) * srs * g0.z + b0.z);
      h[3] = (_Float16)((a0.w - sm) * srs * g0.w + b0.w);
      h[4] = (_Float16)((a1.x - sm) * srs * g1.x + b1.x);
      h[5] = (_Float16)((a1.y - sm) * srs * g1.y + b1.y);
      h[6] = (_Float16)((a1.z - sm) * srs * g1.z + b1.z);
      h[7] = (_Float16)((a1.w - sm) * srs * g1.w + b1.w);
      *(half8*)&xh2[ra][ca + j * 8] = h;
    }
  }
  __syncthreads();

  floatx4 acc2[4][3] = {};   // ff2 accumulators, persist across quarters
  for (int qq = 0; qq < 4; ++qq) {
    // ff1 quarter: FF cols [qq*192, +192). wave w: 48 local cols (3 tiles).
    #pragma unroll
    for (int nt = 0; nt < 3; ++nt) {
      const int ng = qq * 192 + w * 48 + nt * 16;   // global ff col
      const int nl = w * 48 + nt * 16;              // local col in ffh
      half8 bf[6];
      const _Float16* wp = wff1 + (size_t)(ng + ln16) * 192 + quad * 8;
      #pragma unroll
      for (int k = 0; k < 6; ++k) bf[k] = *(const half8*)(wp + k * 32);
      floatx4 a4[4] = {};
      #pragma unroll
      for (int k = 0; k < 6; ++k) {
        #pragma unroll
        for (int mt = 0; mt < 4; ++mt) {
          half8 af = *(const half8*)&xh2[mt * 16 + ln16][k * 32 + quad * 8];
          a4[mt] = __builtin_amdgcn_mfma_f32_16x16x32_f16(af, bf[k], a4[mt], 0, 0, 0);
        }
      }
      const float bv = bff1[ng + ln16];
      #pragma unroll
      for (int mt = 0; mt < 4; ++mt)
        #pragma unroll
        for (int r = 0; r < 4; ++r)
          ffh[mt * 16 + quad * 4 + r][nl + ln16] = (_Float16)gelu_f(a4[mt][r] + bv);
    }
    __syncthreads();
    // ff2 partial: acc2 += FF_quarter @ wff2[:, qq*192..+192)^T slice
    for (int k12 = 0; k12 < 6; ++k12) {
      half8 af[4];
      #pragma unroll
      for (int mt = 0; mt < 4; ++mt)
        af[mt] = *(const half8*)&ffh[mt * 16 + ln16][k12 * 32 + quad * 8];
      #pragma unroll
      for (int nt = 0; nt < 3; ++nt) {
        const int nc = w * 48 + nt * 16;
        half8 bf = *(const half8*)(wff2 + (size_t)(nc + ln16) * 768 +
                                   qq * 192 + k12 * 32 + quad * 8);
        #pragma unroll
        for (int mt = 0; mt < 4; ++mt)
          acc2[mt][nt] = __builtin_amdgcn_mfma_f32_16x16x32_f16(
              af[mt], bf, acc2[mt][nt], 0, 0, 0);
      }
    }
    __syncthreads();   // ffh reads done before overwrite / out staging
  }

  // stage fp32 result (bias added) into whole pool (xh2+ffh both dead)
  float* outs = (float*)pool;   // 64*192*4 = 49152 <= 51200
  #pragma unroll
  for (int nt = 0; nt < 3; ++nt) {
    const int nc = w * 48 + nt * 16;
    const float bv = bff2[nc + ln16];
    #pragma unroll
    for (int mt = 0; mt < 4; ++mt)
      #pragma unroll
      for (int r = 0; r < 4; ++r)
        outs[(mt * 16 + quad * 4 + r) * 192 + nc + ln16] = acc2[mt][nt][r] + bv;
  }
  __syncthreads();

  // coalesced residual add + write + next-layer LN1 stats (4 threads/row)
  {
    const int fbase = tid * 12;     // 3072 float4 total
    const int row = tid >> 2;
    float* xg = x + (size_t)m0 * 192;
    float s = 0.f, q = 0.f;
    #pragma unroll
    for (int j = 0; j < 12; ++j) {
      float4 v = ((const float4*)outs)[fbase + j];
      float4 rr = *(const float4*)(xg + (fbase + j) * 4);
      v.x += rr.x; v.y += rr.y; v.z += rr.z; v.w += rr.w;
      s += v.x + v.y + v.z + v.w;
      q += v.x * v.x + v.y * v.y + v.z * v.z + v.w * v.w;
      *(float4*)(xg + (fbase + j) * 4) = v;
    }
    s += __shfl_xor(s, 1); s += __shfl_xor(s, 2);
    q += __shfl_xor(q, 1); q += __shfl_xor(q, 2);
    if ((tid & 3) == 0) {
      float mean = s * (1.f / 192.f);
      stD[2 * (m0 + row)] = mean;
      stD[2 * (m0 + row) + 1] = rsqrtf(q * (1.f / 192.f) - mean * mean + 1e-5f);
    }
  }
}

// ---------------------------------------------------------------------------
// fp32 GEMM (head only): C[M,N] = epi(A[M,K] @ W[N,K]^T + bias)
// ---------------------------------------------------------------------------
template <int EPI>
__global__ __launch_bounds__(256) void gemm_f32(
    const float* __restrict__ A, const float* __restrict__ W,
    const float* __restrict__ bias, float* __restrict__ C,
    int M, int N, int K) {
  __shared__ float As[16][68];
  __shared__ float Bs[16][68];
  const int tid = threadIdx.x;
  const int m0 = blockIdx.x * 64;
  const int n0 = blockIdx.y * 64;
  const int tx = tid & 15, ty = tid >> 4;
  const int lr = tid >> 2;
  const int lk = (tid & 3) << 2;
  float acc[4][4] = {};
  const float* Arow = A + (size_t)(m0 + lr) * K;
  const float* Wrow = W + (size_t)(n0 + lr) * K;
  for (int k0 = 0; k0 < K; k0 += 16) {
    float4 av = *(const float4*)(Arow + k0 + lk);
    float4 wv = *(const float4*)(Wrow + k0 + lk);
    __syncthreads();
    As[lk + 0][lr] = av.x; As[lk + 1][lr] = av.y;
    As[lk + 2][lr] = av.z; As[lk + 3][lr] = av.w;
    Bs[lk + 0][lr] = wv.x; Bs[lk + 1][lr] = wv.y;
    Bs[lk + 2][lr] = wv.z; Bs[lk + 3][lr] = wv.w;
    __syncthreads();
    #pragma unroll
    for (int kk = 0; kk < 16; ++kk) {
      float4 a = *(const float4*)&As[kk][ty * 4];
      float4 b = *(const float4*)&Bs[kk][tx * 4];
      acc[0][0] += a.x * b.x; acc[0][1] += a.x * b.y; acc[0][2] += a.x * b.z; acc[0][3] += a.x * b.w;
      acc[1][0] += a.y * b.x; acc[1][1] += a.y * b.y; acc[1][2] += a.y * b.z; acc[1][3] += a.y * b.w;
      acc[2][0] += a.z * b.x; acc[2][1] += a.z * b.y; acc[2][2] += a.z * b.z; acc[2][3] += a.z * b.w;
      acc[3][0] += a.w * b.x; acc[3][1] += a.w * b.y; acc[3][2] += a.w * b.z; acc[3][3] += a.w * b.w;
    }
  }
  float4 bv = *(const float4*)(bias + n0 + tx * 4);
  #pragma unroll
  for (int i = 0; i < 4; ++i) {
    int m = m0 + ty * 4 + i;
    float v0 = acc[i][0] + bv.x, v1 = acc[i][1] + bv.y;
    float v2 = acc[i][2] + bv.z, v3 = acc[i][3] + bv.w;
    if constexpr (EPI == 1) {
      v0 = gelu_f(v0); v1 = gelu_f(v1); v2 = gelu_f(v2); v3 = gelu_f(v3);
    }
    float4 ov; ov.x = v0; ov.y = v1; ov.z = v2; ov.w = v3;
    *(float4*)(C + (size_t)m * N + n0 + tx * 4) = ov;
  }
}

// ---------------------------------------------------------------------------
// mean-pool over S=4 + head LN (one wave per sample)
// ---------------------------------------------------------------------------
__global__ __launch_bounds__(256) void pool_ln_kernel(const float* __restrict__ x,
                                                      const float* __restrict__ g,
                                                      const float* __restrict__ b,
                                                      float* __restrict__ hout) {
  int bi = blockIdx.x * 4 + (threadIdx.x >> 6);
  int lane = threadIdx.x & 63;
  const float* row = x + (size_t)bi * 4 * D_;
  float vals[3];
  float sum = 0.f;
  #pragma unroll
  for (int cc = 0; cc < 3; ++cc) {
    int d = lane + cc * 64;
    float v = 0.25f * (row[d] + row[D_ + d] + row[2 * D_ + d] + row[3 * D_ + d]);
    vals[cc] = v; sum += v;
  }
  #pragma unroll
  for (int off = 1; off < 64; off <<= 1) sum += __shfl_xor(sum, off);
  float mean = sum / (float)D_;
  float vs = 0.f;
  #pragma unroll
  for (int cc = 0; cc < 3; ++cc) { float d0 = vals[cc] - mean; vs += d0 * d0; }
  #pragma unroll
  for (int off = 1; off < 64; off <<= 1) vs += __shfl_xor(vs, off);
  float rstd = rsqrtf(vs / (float)D_ + 1e-5f);
  #pragma unroll
  for (int cc = 0; cc < 3; ++cc) {
    int d = lane + cc * 64;
    hout[(size_t)bi * D_ + d] = (vals[cc] - mean) * rstd * g[d] + b[d];
  }
}

// ---------------------------------------------------------------------------
// final: out[b] = h2[b,:64] . h3_w + h3_b  (one wave per sample)
// ---------------------------------------------------------------------------
__global__ __launch_bounds__(256) void head_final_kernel(const float* __restrict__ h2,
                                                         const float* __restrict__ w,
                                                         const float* __restrict__ b,
                                                         float* __restrict__ out) {
  int bi = blockIdx.x * 4 + (threadIdx.x >> 6);
  int lane = threadIdx.x & 63;
  float v = h2[(size_t)bi * 64 + lane] * w[lane];
  #pragma unroll
  for (int off = 1; off < 64; off <<= 1) v += __shfl_xor(v, off);
  if (lane == 0) out[bi] = v + b[0];
}

// ---------------------------------------------------------------------------
extern "C" void kernel_launch(void* const* d_in, const int* in_sizes, int n_in,
                              void* d_out, int out_size, void* d_ws, size_t ws_size,
                              hipStream_t stream) {
  (void)in_sizes; (void)n_in; (void)out_size; (void)ws_size;
  const float* emb       = (const float*)d_in[0];
  const float* in_ln_w   = (const float*)d_in[1];
  const float* in_ln_b   = (const float*)d_in[2];
  const float* in_proj_w = (const float*)d_in[3];
  const float* in_proj_b = (const float*)d_in[4];
  const float* qkv_w     = (const float*)d_in[5];
  const float* qkv_b     = (const float*)d_in[6];
  const float* aow       = (const float*)d_in[7];
  const float* aob       = (const float*)d_in[8];
  const float* ln1w      = (const float*)d_in[9];
  const float* ln1b      = (const float*)d_in[10];
  const float* ln2w      = (const float*)d_in[11];
  const float* ln2b      = (const float*)d_in[12];
  const float* ff1w      = (const float*)d_in[13];
  const float* ff1b      = (const float*)d_in[14];
  const float* ff2w      = (const float*)d_in[15];
  const float* ff2b      = (const float*)d_in[16];
  const float* hlnw      = (const float*)d_in[17];
  const float* hlnb      = (const float*)d_in[18];
  const float* h1w       = (const float*)d_in[19];
  const float* h1b       = (const float*)d_in[20];
  const float* h2w       = (const float*)d_in[21];
  const float* h2b       = (const float*)d_in[22];
  const float* h3w       = (const float*)d_in[23];
  const float* h3b       = (const float*)d_in[24];
  float* out = (float*)d_out;

  float* ws = (float*)d_ws;
  size_t off = 0;
  float* x   = ws + off; off += (size_t)MTOK * D_;   // fp32 residual stream
  float* stD = ws + off; off += (size_t)MTOK * 2;    // per-token LN stats
  float* hp  = ws + off; off += (size_t)B_ * D_;
  float* h1  = ws + off; off += (size_t)B_ * 256;
  float* h2  = ws + off; off += (size_t)B_ * 64;
  float* c1  = ws + off; off += 192;                 // in_proj LN-fold consts
  float* c2  = ws + off; off += 192;
  // fp16 weight pack region
  _Float16* wh = (_Float16*)(ws + off);
  _Float16* w_inproj = wh;                       // 192*1152  = 221184
  _Float16* w_qkv    = w_inproj + 221184;        // 2*576*192 = 221184
  _Float16* w_ao     = w_qkv    + 221184;        // 2*192*192 =  73728
  _Float16* w_ff1    = w_ao     + 73728;         // 2*768*192 = 294912
  _Float16* w_ff2    = w_ff1    + 294912;        // 2*192*768 = 294912

  prep_inproj_w<<<48, 256, 0, stream>>>(in_proj_w, in_ln_w, in_ln_b, in_proj_b,
                                        w_inproj, c1, c2);
  cvt_f16_kernel<<<221184 / 2048, 256, 0, stream>>>(qkv_w, w_qkv);
  cvt_f16_kernel<<<73728  / 2048, 256, 0, stream>>>(aow, w_ao);
  cvt_f16_kernel<<<294912 / 2048, 256, 0, stream>>>(ff1w, w_ff1);
  cvt_f16_kernel<<<294912 / 2048, 256, 0, stream>>>(ff2w, w_ff2);

  inproj2_kernel<<<MTOK / 64, 256, 0, stream>>>(emb, w_inproj, c1, c2, x, stD);

  for (int i = 0; i < NL_; ++i) {
    layer_attn_kernel<<<MTOK / 32, 256, 0, stream>>>(
        x, w_qkv + (size_t)i * 110592, qkv_b + (size_t)i * 576,
        w_ao + (size_t)i * 36864, aob + (size_t)i * 192,
        ln1w + (size_t)i * 192, ln1b + (size_t)i * 192, stD);
    layer_ff_kernel<<<MTOK / 64, 256, 0, stream>>>(
        x, w_ff1 + (size_t)i * 147456, ff1b + (size_t)i * 768,
        w_ff2 + (size_t)i * 147456, ff2b + (size_t)i * 192,
        ln2w + (size_t)i * 192, ln2b + (size_t)i * 192, stD);
  }

  pool_ln_kernel<<<B_ / 4, 256, 0, stream>>>(x, hlnw, hlnb, hp);
  gemm_f32<1><<<dim3(B_ / 64, 256 / 64), 256, 0, stream>>>(hp, h1w, h1b, h1, B_, 256, D_);
  gemm_f32<1><<<dim3(B_ / 64, 64 / 64), 256, 0, stream>>>(h1, h2w, h2b, h2, B_, 64, 256);
  head_final_kernel<<<B_ / 4, 256, 0, stream>>>(h2, h3w, h3b, out);
}

// Round 7
// 973.891 us; speedup vs baseline: 1.2185x; 1.0253x over previous
//
#include <hip/hip_runtime.h>
#include <hip/hip_bf16.h>
#include <math.h>

#define B_   16384
#define S_   4
#define E_   1152
#define D_   192
#define FF_  768
#define NL_  2
#define MTOK (B_ * S_)   // 65536 tokens

typedef __attribute__((ext_vector_type(8))) _Float16 half8;
typedef __attribute__((ext_vector_type(4))) float floatx4;

__device__ __forceinline__ float gelu_f(float x) {
  return 0.5f * x * (1.0f + erff(x * 0.70710678118654752f));
}

// ---------------------------------------------------------------------------
// fp32 -> fp16 weight pre-pack (total elems % 2048 == 0)
// ---------------------------------------------------------------------------
__global__ __launch_bounds__(256) void cvt_f16_kernel(const float* __restrict__ s,
                                                      _Float16* __restrict__ d) {
  int i = (blockIdx.x * 256 + threadIdx.x) * 8;
  float4 a = *(const float4*)(s + i);
  float4 b = *(const float4*)(s + i + 4);
  half8 h;
  h[0] = (_Float16)a.x; h[1] = (_Float16)a.y; h[2] = (_Float16)a.z; h[3] = (_Float16)a.w;
  h[4] = (_Float16)b.x; h[5] = (_Float16)b.y; h[6] = (_Float16)b.z; h[7] = (_Float16)b.w;
  *(half8*)(d + i) = h;
}

// ---------------------------------------------------------------------------
// in_proj weight prep: fold input-LN into the weight.
//   Wh[n][k] = fp16(g[k] * W[n][k])
//   c1[n]    = sum_k (float)Wh[n][k]
//   c2[n]    = sum_k b[k]*W[n][k] + bias[n]
// LN(x) @ W^T + bias = rs*( x @ Wh^T - m*c1 ) + c2  per row (m, rs).
// ---------------------------------------------------------------------------
__global__ __launch_bounds__(256) void prep_inproj_w(
    const float* __restrict__ W, const float* __restrict__ g,
    const float* __restrict__ b, const float* __restrict__ bias,
    _Float16* __restrict__ Wh, float* __restrict__ c1, float* __restrict__ c2) {
  const int n = blockIdx.x * 4 + (threadIdx.x >> 6);
  const int lane = threadIdx.x & 63;
  const float* Wr = W + (size_t)n * 1152;
  _Float16* Whr = Wh + (size_t)n * 1152;
  float s1 = 0.f, s2 = 0.f;
  #pragma unroll
  for (int j = 0; j < 18; ++j) {
    int k = lane + 64 * j;
    float wv = Wr[k];
    _Float16 h = (_Float16)(wv * g[k]);
    Whr[k] = h;
    s1 += (float)h;
    s2 = fmaf(b[k], wv, s2);
  }
  #pragma unroll
  for (int off = 1; off < 64; off <<= 1) {
    s1 += __shfl_xor(s1, off);
    s2 += __shfl_xor(s2, off);
  }
  if (lane == 0) { c1[n] = s1; c2[n] = s2 + bias[n]; }
}

// ---------------------------------------------------------------------------
// in_proj v2: x[M,192] = posenc(GELU( rs*(emb@Wh^T - m*c1) + c2 ))  (proven)
// ---------------------------------------------------------------------------
__global__ __launch_bounds__(256) void inproj2_kernel(
    const float* __restrict__ emb, const _Float16* __restrict__ whp,
    const float* __restrict__ c1g, const float* __restrict__ c2g,
    float* __restrict__ xout, float* __restrict__ stD) {
  __shared__ __align__(16) _Float16 As[64][72];   // padded: conflict-free frags
  __shared__ float stats_[64][2];                 // emb-row (mean, rstd)
  __shared__ float red_[4][64][2];                // per-wave output-stat partials
  __shared__ float pe_[4][192];                   // posenc table
  const int tid = threadIdx.x;
  const int m0 = blockIdx.x * 64;
  const int w = tid >> 6, lane = tid & 63;
  const int ln16 = lane & 15, quad = lane >> 4;
  const int r_a = tid >> 2;            // 0..63 (A-stage row)
  const int c_a = (tid & 3) * 16;      // 0/16/32/48 within BK=64

  // posenc table (768 entries, 3 per thread)
  for (int i = tid; i < 768; i += 256) {
    int r = i / 192, col = i - r * 192;
    float ang = (float)r * expf((float)(col & ~1) * (-0.047970522770709292f));
    pe_[r][col] = (col & 1) ? cosf(ang) : sinf(ang);
  }

  const float* Arow = emb + (size_t)(m0 + r_a) * 1152 + c_a;
  const _Float16* wb = whp + (size_t)(w * 48 + ln16) * 1152 + quad * 8;

  float4 pa[4];
  auto loadA = [&](int k0) {
    #pragma unroll
    for (int j = 0; j < 4; ++j) pa[j] = *(const float4*)(Arow + k0 + j * 4);
  };

  float s = 0.f, q = 0.f;
  floatx4 acc[4][3] = {};
  loadA(0);
  for (int k0 = 0; k0 < 1152; k0 += 64) {
    __syncthreads();   // prior-iter fragment reads of As complete
    half8 h0, h1;
    h0[0] = (_Float16)pa[0].x; h0[1] = (_Float16)pa[0].y;
    h0[2] = (_Float16)pa[0].z; h0[3] = (_Float16)pa[0].w;
    h0[4] = (_Float16)pa[1].x; h0[5] = (_Float16)pa[1].y;
    h0[6] = (_Float16)pa[1].z; h0[7] = (_Float16)pa[1].w;
    h1[0] = (_Float16)pa[2].x; h1[1] = (_Float16)pa[2].y;
    h1[2] = (_Float16)pa[2].z; h1[3] = (_Float16)pa[2].w;
    h1[4] = (_Float16)pa[3].x; h1[5] = (_Float16)pa[3].y;
    h1[6] = (_Float16)pa[3].z; h1[7] = (_Float16)pa[3].w;
    *(half8*)&As[r_a][c_a] = h0;
    *(half8*)&As[r_a][c_a + 8] = h1;
    #pragma unroll
    for (int j = 0; j < 4; ++j) {
      s += pa[j].x + pa[j].y + pa[j].z + pa[j].w;
      q = fmaf(pa[j].x, pa[j].x, q); q = fmaf(pa[j].y, pa[j].y, q);
      q = fmaf(pa[j].z, pa[j].z, q); q = fmaf(pa[j].w, pa[j].w, q);
    }
    __syncthreads();   // As visible
    if (k0 + 64 < 1152) loadA(k0 + 64);   // prefetch overlaps compute below
    #pragma unroll
    for (int kk = 0; kk < 64; kk += 32) {
      half8 af[4], bf[3];
      #pragma unroll
      for (int mt = 0; mt < 4; ++mt)
        af[mt] = *(const half8*)&As[mt * 16 + ln16][kk + quad * 8];
      #pragma unroll
      for (int nt = 0; nt < 3; ++nt)
        bf[nt] = *(const half8*)(wb + (size_t)nt * 16 * 1152 + k0 + kk);
      #pragma unroll
      for (int mt = 0; mt < 4; ++mt)
        #pragma unroll
        for (int nt = 0; nt < 3; ++nt)
          acc[mt][nt] = __builtin_amdgcn_mfma_f32_16x16x32_f16(
              af[mt], bf[nt], acc[mt][nt], 0, 0, 0);
    }
  }

  // finalize emb-row LN stats (4 threads per row)
  s += __shfl_xor(s, 1); s += __shfl_xor(s, 2);
  q += __shfl_xor(q, 1); q += __shfl_xor(q, 2);
  if ((tid & 3) == 0) {
    float mean = s * (1.f / 1152.f);
    stats_[r_a][0] = mean;
    stats_[r_a][1] = rsqrtf(q * (1.f / 1152.f) - mean * mean + 1e-5f);
  }
  __syncthreads();

  // epilogue: correction + GELU + posenc, direct coalesced stores,
  // fused output LN1 stats (16-lane shuffle reduce -> LDS -> combine)
  float c1v[3], c2v[3];
  #pragma unroll
  for (int nt = 0; nt < 3; ++nt) {
    c1v[nt] = c1g[w * 48 + nt * 16 + ln16];
    c2v[nt] = c2g[w * 48 + nt * 16 + ln16];
  }
  float* xg = xout + (size_t)m0 * 192;
  #pragma unroll
  for (int mt = 0; mt < 4; ++mt) {
    #pragma unroll
    for (int r = 0; r < 4; ++r) {
      const int row = mt * 16 + quad * 4 + r;   // (global row)&3 == r
      const float rm = stats_[row][0], rr = stats_[row][1];
      float so = 0.f, qo = 0.f;
      #pragma unroll
      for (int nt = 0; nt < 3; ++nt) {
        const int col = w * 48 + nt * 16 + ln16;
        float v = rr * (acc[mt][nt][r] - rm * c1v[nt]) + c2v[nt];
        v = gelu_f(v);
        v += pe_[r][col];
        xg[(size_t)row * 192 + col] = v;
        so += v;
        qo = fmaf(v, v, qo);
      }
      so += __shfl_xor(so, 1); so += __shfl_xor(so, 2);
      so += __shfl_xor(so, 4); so += __shfl_xor(so, 8);
      qo += __shfl_xor(qo, 1); qo += __shfl_xor(qo, 2);
      qo += __shfl_xor(qo, 4); qo += __shfl_xor(qo, 8);
      if (ln16 == 0) { red_[w][row][0] = so; red_[w][row][1] = qo; }
    }
  }
  __syncthreads();
  if (tid < 64) {
    float so = red_[0][tid][0] + red_[1][tid][0] + red_[2][tid][0] + red_[3][tid][0];
    float qo = red_[0][tid][1] + red_[1][tid][1] + red_[2][tid][1] + red_[3][tid][1];
    float mean = so * (1.f / 192.f);
    stD[2 * (m0 + tid)] = mean;
    stD[2 * (m0 + tid) + 1] = rsqrtf(qo * (1.f / 192.f) - mean * mean + 1e-5f);
  }
}

// ---------------------------------------------------------------------------
// Fused attention block (per layer): x += attn_out(attn(qkv(LN1(x))))
// BM=32 tokens = 8 samples/block. (proven)
// ---------------------------------------------------------------------------
__global__ __launch_bounds__(256) void layer_attn_kernel(
    float* __restrict__ x, const _Float16* __restrict__ wqkv,
    const float* __restrict__ bqkv, const _Float16* __restrict__ wao,
    const float* __restrict__ bao, const float* __restrict__ ln1g,
    const float* __restrict__ ln1b_, float* __restrict__ stD) {
  __shared__ __align__(16) _Float16 xh[32][200];   // LN1(x), then o
  __shared__ __align__(16) _Float16 qk[32][584];   // qkv, then fp32 out stage
  __shared__ float sp[8][4][4][4];
  const int tid = threadIdx.x;
  const int m0 = blockIdx.x * 32;
  const int w = tid >> 6, lane = tid & 63;
  const int ln16 = lane & 15, quad = lane >> 4;

  // phase 0: LN1(x) -> xh (8 threads per row, 24 floats each)
  {
    const int ra = tid >> 3, ca = (tid & 7) * 24;
    const float sm = stD[2 * (m0 + ra)], srs = stD[2 * (m0 + ra) + 1];
    const float* Ar = x + (size_t)(m0 + ra) * 192 + ca;
    #pragma unroll
    for (int j = 0; j < 3; ++j) {
      float4 a0 = *(const float4*)(Ar + j * 8);
      float4 a1 = *(const float4*)(Ar + j * 8 + 4);
      float4 g0 = *(const float4*)(ln1g + ca + j * 8);
      float4 g1 = *(const float4*)(ln1g + ca + j * 8 + 4);
      float4 b0 = *(const float4*)(ln1b_ + ca + j * 8);
      float4 b1 = *(const float4*)(ln1b_ + ca + j * 8 + 4);
      half8 h;
      h[0] = (_Float16)((a0.x - sm) * srs * g0.x + b0.x);
      h[1] = (_Float16)((a0.y - sm) * srs * g0.y + b0.y);
      h[2] = (_Float16)((a0.z - sm) * srs * g0.z + b0.z);
      h[3] = (_Float16)((a0.w - sm) * srs * g0.w + b0.w);
      h[4] = (_Float16)((a1.x - sm) * srs * g1.x + b1.x);
      h[5] = (_Float16)((a1.y - sm) * srs * g1.y + b1.y);
      h[6] = (_Float16)((a1.z - sm) * srs * g1.z + b1.z);
      h[7] = (_Float16)((a1.w - sm) * srs * g1.w + b1.w);
      *(half8*)&xh[ra][ca + j * 8] = h;
    }
  }
  __syncthreads();

  // phase 1: qkv -> qk LDS. wave w covers cols [w*144, w*144+144) (9 tiles)
  for (int nt = 0; nt < 9; ++nt) {
    const int nc = w * 144 + nt * 16;
    half8 bf[6];
    const _Float16* wp = wqkv + (size_t)(nc + ln16) * 192 + quad * 8;
    #pragma unroll
    for (int k = 0; k < 6; ++k) bf[k] = *(const half8*)(wp + k * 32);
    floatx4 a0v = {}, a1v = {};
    #pragma unroll
    for (int k = 0; k < 6; ++k) {
      half8 f0 = *(const half8*)&xh[ln16][k * 32 + quad * 8];
      half8 f1 = *(const half8*)&xh[16 + ln16][k * 32 + quad * 8];
      a0v = __builtin_amdgcn_mfma_f32_16x16x32_f16(f0, bf[k], a0v, 0, 0, 0);
      a1v = __builtin_amdgcn_mfma_f32_16x16x32_f16(f1, bf[k], a1v, 0, 0, 0);
    }
    const float bv = bqkv[nc + ln16];
    #pragma unroll
    for (int r = 0; r < 4; ++r) {
      qk[quad * 4 + r][nc + ln16]      = (_Float16)(a0v[r] + bv);
      qk[16 + quad * 4 + r][nc + ln16] = (_Float16)(a1v[r] + bv);
    }
  }
  __syncthreads();

  // phase 2: attention. wave w handles samples 2w, 2w+1 (rows 4sg..4sg+3).
  #pragma unroll
  for (int s2 = 0; s2 < 2; ++s2) {
    const int sg = w * 2 + s2;
    const int h = lane >> 4, i = (lane >> 2) & 3, j = lane & 3;
    const _Float16* qp = &qk[4 * sg + i][h * 48];
    const _Float16* kp = &qk[4 * sg + j][192 + h * 48];
    float s = 0.f;
    #pragma unroll
    for (int d = 0; d < 6; ++d) {
      half8 qv = *(const half8*)(qp + d * 8);
      half8 kv = *(const half8*)(kp + d * 8);
      #pragma unroll
      for (int e = 0; e < 8; ++e) s += (float)qv[e] * (float)kv[e];
    }
    s *= 0.14433756729740643f;  // 1/sqrt(48)
    float mx = fmaxf(s, __shfl_xor(s, 1));
    mx = fmaxf(mx, __shfl_xor(mx, 2));
    float e = expf(s - mx);
    float sum = e + __shfl_xor(e, 1);
    sum += __shfl_xor(sum, 2);
    sp[sg][h][i][j] = e / sum;   // wave-local; same wave reads below
  }
  #pragma unroll
  for (int s2 = 0; s2 < 2; ++s2) {
    const int sg = w * 2 + s2;
    #pragma unroll
    for (int ii = 0; ii < 4; ++ii) {
      #pragma unroll
      for (int cc = 0; cc < 3; ++cc) {
        const int c = lane + cc * 64;
        const int hh = c / 48;
        float a = 0.f;
        #pragma unroll
        for (int jj = 0; jj < 4; ++jj)
          a += sp[sg][hh][ii][jj] * (float)qk[4 * sg + jj][384 + c];
        xh[4 * sg + ii][c] = (_Float16)a;   // o overwrites LN1 tile (reads done)
      }
    }
  }
  __syncthreads();

  // phase 3: attn_out GEMM. wave w cols [w*48, w*48+48).
  float* outs = (float*)&qk[0][0];   // 32*192*4 = 24576 B <= 37376 B
  #pragma unroll
  for (int nt = 0; nt < 3; ++nt) {
    const int nc = w * 48 + nt * 16;
    half8 bf[6];
    const _Float16* wp = wao + (size_t)(nc + ln16) * 192 + quad * 8;
    #pragma unroll
    for (int k = 0; k < 6; ++k) bf[k] = *(const half8*)(wp + k * 32);
    floatx4 a0v = {}, a1v = {};
    #pragma unroll
    for (int k = 0; k < 6; ++k) {
      half8 f0 = *(const half8*)&xh[ln16][k * 32 + quad * 8];
      half8 f1 = *(const half8*)&xh[16 + ln16][k * 32 + quad * 8];
      a0v = __builtin_amdgcn_mfma_f32_16x16x32_f16(f0, bf[k], a0v, 0, 0, 0);
      a1v = __builtin_amdgcn_mfma_f32_16x16x32_f16(f1, bf[k], a1v, 0, 0, 0);
    }
    const float bv = bao[nc + ln16];
    #pragma unroll
    for (int r = 0; r < 4; ++r) {
      outs[(quad * 4 + r) * 192 + nc + ln16]      = a0v[r] + bv;
      outs[(16 + quad * 4 + r) * 192 + nc + ln16] = a1v[r] + bv;
    }
  }
  __syncthreads();

  // phase 4: coalesced residual add + write + LN2 stats (8 threads per row)
  {
    const int fbase = tid * 6;      // 1536 float4 total
    const int row = tid >> 3;
    float* xg = x + (size_t)m0 * 192;
    float s = 0.f, q = 0.f;
    #pragma unroll
    for (int j = 0; j < 6; ++j) {
      float4 v = ((const float4*)outs)[fbase + j];
      float4 rr = *(const float4*)(xg + (fbase + j) * 4);
      v.x += rr.x; v.y += rr.y; v.z += rr.z; v.w += rr.w;
      s += v.x + v.y + v.z + v.w;
      q += v.x * v.x + v.y * v.y + v.z * v.z + v.w * v.w;
      *(float4*)(xg + (fbase + j) * 4) = v;
    }
    s += __shfl_xor(s, 1); s += __shfl_xor(s, 2); s += __shfl_xor(s, 4);
    q += __shfl_xor(q, 1); q += __shfl_xor(q, 2); q += __shfl_xor(q, 4);
    if ((tid & 7) == 0) {
      float mean = s * (1.f / 192.f);
      stD[2 * (m0 + row)] = mean;
      stD[2 * (m0 + row) + 1] = rsqrtf(q * (1.f / 192.f) - mean * mean + 1e-5f);
    }
  }
}

// ---------------------------------------------------------------------------
// Fused FF block (per layer): x += ff2(GELU(ff1(LN2(x))))  (proven, quarters)
// ---------------------------------------------------------------------------
__global__ __launch_bounds__(256) void layer_ff_kernel(
    float* __restrict__ x, const _Float16* __restrict__ wff1,
    const float* __restrict__ bff1, const _Float16* __restrict__ wff2,
    const float* __restrict__ bff2, const float* __restrict__ ln2g,
    const float* __restrict__ ln2b_, float* __restrict__ stD) {
  __shared__ __align__(16) char pool[51200];
  _Float16 (*xh2)[200] = (_Float16 (*)[200])pool;            // LN2(x)  [0,25600)
  _Float16 (*ffh)[200] = (_Float16 (*)[200])(pool + 25600);  // FF qtr [25600,51200)
  const int tid = threadIdx.x;
  const int m0 = blockIdx.x * 64;
  const int w = tid >> 6, lane = tid & 63;
  const int ln16 = lane & 15, quad = lane >> 4;

  // phase 0: LN2(x) -> xh2 (4 threads per row, 48 floats each)
  {
    const int ra = tid >> 2, ca = (tid & 3) * 48;
    const float sm = stD[2 * (m0 + ra)], srs = stD[2 * (m0 + ra) + 1];
    const float* Ar = x + (size_t)(m0 + ra) * 192 + ca;
    #pragma unroll
    for (int j = 0; j < 6; ++j) {
      float4 a0 = *(const float4*)(Ar + j * 8);
      float4 a1 = *(const float4*)(Ar + j * 8 + 4);
      float4 g0 = *(const float4*)(ln2g + ca + j * 8);
      float4 g1 = *(const float4*)(ln2g + ca + j * 8 + 4);
      float4 b0 = *(const float4*)(ln2b_ + ca + j * 8);
      float4 b1 = *(const float4*)(ln2b_ + ca + j * 8 + 4);
      half8 h;
      h[0] = (_Float16)((a0.x - sm) * srs * g0.x + b0.x);
      h[1] = (_Float16)((a0.y - sm) * srs * g0.y + b0.y);
      h[2] = (_Float16)((a0.z - sm) * srs * g0.z + b0.z);
      h[3] = (_Float16)((a0.w - sm) * srs * g0.w + b0.w);
      h[4] = (_Float16)((a1.x - sm) * srs * g1.x + b1.x);
      h[5] = (_Float16)((a1.y - sm) * srs * g1.y + b1.y);
      h[6] = (_Float16)((a1.z - sm) * srs * g1.z + b1.z);
      h[7] = (_Float16)((a1.w - sm) * srs * g1.w + b1.w);
      *(half8*)&xh2[ra][ca + j * 8] = h;
    }
  }
  __syncthreads();

  floatx4 acc2[4][3] = {};   // ff2 accumulators, persist across quarters
  for (int qq = 0; qq < 4; ++qq) {
    // ff1 quarter: FF cols [qq*192, +192). wave w: 48 local cols (3 tiles).
    #pragma unroll
    for (int nt = 0; nt < 3; ++nt) {
      const int ng = qq * 192 + w * 48 + nt * 16;   // global ff col
      const int nl = w * 48 + nt * 16;              // local col in ffh
      half8 bf[6];
      const _Float16* wp = wff1 + (size_t)(ng + ln16) * 192 + quad * 8;
      #pragma unroll
      for (int k = 0; k < 6; ++k) bf[k] = *(const half8*)(wp + k * 32);
      floatx4 a4[4] = {};
      #pragma unroll
      for (int k = 0; k < 6; ++k) {
        #pragma unroll
        for (int mt = 0; mt < 4; ++mt) {
          half8 af = *(const half8*)&xh2[mt * 16 + ln16][k * 32 + quad * 8];
          a4[mt] = __builtin_amdgcn_mfma_f32_16x16x32_f16(af, bf[k], a4[mt], 0, 0, 0);
        }
      }
      const float bv = bff1[ng + ln16];
      #pragma unroll
      for (int mt = 0; mt < 4; ++mt)
        #pragma unroll
        for (int r = 0; r < 4; ++r)
          ffh[mt * 16 + quad * 4 + r][nl + ln16] = (_Float16)gelu_f(a4[mt][r] + bv);
    }
    __syncthreads();
    // ff2 partial: acc2 += FF_quarter @ wff2[:, qq*192..+192)^T slice
    for (int k12 = 0; k12 < 6; ++k12) {
      half8 af[4];
      #pragma unroll
      for (int mt = 0; mt < 4; ++mt)
        af[mt] = *(const half8*)&ffh[mt * 16 + ln16][k12 * 32 + quad * 8];
      #pragma unroll
      for (int nt = 0; nt < 3; ++nt) {
        const int nc = w * 48 + nt * 16;
        half8 bf = *(const half8*)(wff2 + (size_t)(nc + ln16) * 768 +
                                   qq * 192 + k12 * 32 + quad * 8);
        #pragma unroll
        for (int mt = 0; mt < 4; ++mt)
          acc2[mt][nt] = __builtin_amdgcn_mfma_f32_16x16x32_f16(
              af[mt], bf, acc2[mt][nt], 0, 0, 0);
      }
    }
    __syncthreads();   // ffh reads done before overwrite / out staging
  }

  // stage fp32 result (bias added) into whole pool (xh2+ffh both dead)
  float* outs = (float*)pool;   // 64*192*4 = 49152 <= 51200
  #pragma unroll
  for (int nt = 0; nt < 3; ++nt) {
    const int nc = w * 48 + nt * 16;
    const float bv = bff2[nc + ln16];
    #pragma unroll
    for (int mt = 0; mt < 4; ++mt)
      #pragma unroll
      for (int r = 0; r < 4; ++r)
        outs[(mt * 16 + quad * 4 + r) * 192 + nc + ln16] = acc2[mt][nt][r] + bv;
  }
  __syncthreads();

  // coalesced residual add + write + next-layer LN1 stats (4 threads/row)
  {
    const int fbase = tid * 12;     // 3072 float4 total
    const int row = tid >> 2;
    float* xg = x + (size_t)m0 * 192;
    float s = 0.f, q = 0.f;
    #pragma unroll
    for (int j = 0; j < 12; ++j) {
      float4 v = ((const float4*)outs)[fbase + j];
      float4 rr = *(const float4*)(xg + (fbase + j) * 4);
      v.x += rr.x; v.y += rr.y; v.z += rr.z; v.w += rr.w;
      s += v.x + v.y + v.z + v.w;
      q += v.x * v.x + v.y * v.y + v.z * v.z + v.w * v.w;
      *(float4*)(xg + (fbase + j) * 4) = v;
    }
    s += __shfl_xor(s, 1); s += __shfl_xor(s, 2);
    q += __shfl_xor(q, 1); q += __shfl_xor(q, 2);
    if ((tid & 3) == 0) {
      float mean = s * (1.f / 192.f);
      stD[2 * (m0 + row)] = mean;
      stD[2 * (m0 + row) + 1] = rsqrtf(q * (1.f / 192.f) - mean * mean + 1e-5f);
    }
  }
}

// ---------------------------------------------------------------------------
// Fused head: per 32 tokens (8 samples): mean-pool + head LN + h1 + h2 + h3.
// Byte-for-byte transplant of the Round-3 mega kernel's head tail (proven
// numerics: passed at absmax 1.22e-4), with x staged from global instead of
// residual registers. LDS 31 KB.
// ---------------------------------------------------------------------------
__global__ __launch_bounds__(256) void head_kernel(
    const float* __restrict__ x,
    const float* __restrict__ hlng, const float* __restrict__ hlnb,
    const _Float16* __restrict__ h1wh, const float* __restrict__ h1b,
    const _Float16* __restrict__ h2wh, const float* __restrict__ h2b,
    const float* __restrict__ h3w, const float* __restrict__ h3b,
    float* __restrict__ out) {
  __shared__ __align__(16) _Float16 ph[16][200];       // pooled+LN fp16
  __shared__ __align__(16) char pool[24576];           // xs / h1s / h2s
  const int tid = threadIdx.x;
  const int m0 = blockIdx.x * 32;
  const int w = tid >> 6, lane = tid & 63;
  const int ln16 = lane & 15, quad = lane >> 4;

  // stage x[32 rows] fp32 -> pool (coalesced; 8 threads/row, 24 floats)
  {
    float* xs = (float*)pool;
    const int fbase = tid * 6;
    const float* xg = x + (size_t)m0 * 192;
    #pragma unroll
    for (int j = 0; j < 6; ++j)
      *(float4*)(xs + (fbase + j) * 4) = *(const float4*)(xg + (fbase + j) * 4);
  }
  __syncthreads();

  // pooled + head LN -> ph (rows 8..15 zeroed)   [R3 code]
  {
    const float* xs = (const float*)pool;
    const int s = tid >> 5, u = tid & 31;
    float pv[6];
    float ss = 0.f, qq = 0.f;
    #pragma unroll
    for (int c6 = 0; c6 < 6; ++c6) {
      const int c = u * 6 + c6;
      float v = 0.25f * (xs[(4 * s) * 192 + c] + xs[(4 * s + 1) * 192 + c] +
                         xs[(4 * s + 2) * 192 + c] + xs[(4 * s + 3) * 192 + c]);
      pv[c6] = v; ss += v; qq = fmaf(v, v, qq);
    }
    ss += __shfl_xor(ss, 1); ss += __shfl_xor(ss, 2); ss += __shfl_xor(ss, 4);
    ss += __shfl_xor(ss, 8); ss += __shfl_xor(ss, 16);
    qq += __shfl_xor(qq, 1); qq += __shfl_xor(qq, 2); qq += __shfl_xor(qq, 4);
    qq += __shfl_xor(qq, 8); qq += __shfl_xor(qq, 16);
    const float mean = ss * (1.f / 192.f);
    const float rs = rsqrtf(qq * (1.f / 192.f) - mean * mean + 1e-5f);
    #pragma unroll
    for (int c6 = 0; c6 < 6; ++c6) {
      const int c = u * 6 + c6;
      ph[s][c] = (_Float16)((pv[c6] - mean) * rs * hlng[c] + hlnb[c]);
      ph[8 + s][c] = (_Float16)0.f;
    }
  }
  __syncthreads();

  // h1: [8x192] @ [256x192]^T -> h1s fp16 (rows 8..15 zero). 16 tiles, 4/wave.
  _Float16 (*h1s)[264] = (_Float16 (*)[264])pool;   // 16*264*2 = 8448 B
  #pragma unroll
  for (int nt = 0; nt < 4; ++nt) {
    const int nc = w * 64 + nt * 16;
    half8 bf[6];
    const _Float16* wp = h1wh + (size_t)(nc + ln16) * 192 + quad * 8;
    #pragma unroll
    for (int k = 0; k < 6; ++k) bf[k] = *(const half8*)(wp + k * 32);
    floatx4 a4 = {};
    #pragma unroll
    for (int k = 0; k < 6; ++k) {
      half8 af = *(const half8*)&ph[ln16][k * 32 + quad * 8];
      a4 = __builtin_amdgcn_mfma_f32_16x16x32_f16(af, bf[k], a4, 0, 0, 0);
    }
    const float bv = h1b[nc + ln16];
    #pragma unroll
    for (int r = 0; r < 4; ++r) {
      const int rr = quad * 4 + r;
      h1s[rr][nc + ln16] = (rr < 8) ? (_Float16)gelu_f(a4[r] + bv) : (_Float16)0.f;
    }
  }
  __syncthreads();

  // h2: [8x256] @ [64x256]^T -> h2s fp16. 4 tiles, 1/wave, K=256.
  _Float16 (*h2s)[72] = (_Float16 (*)[72])(pool + 16384);   // 2304 B
  {
    const int nc = w * 16;
    floatx4 a4 = {};
    #pragma unroll
    for (int k = 0; k < 8; ++k) {
      half8 af = *(const half8*)&h1s[ln16][k * 32 + quad * 8];
      half8 bf = *(const half8*)(h2wh + (size_t)(nc + ln16) * 256 + k * 32 + quad * 8);
      a4 = __builtin_amdgcn_mfma_f32_16x16x32_f16(af, bf, a4, 0, 0, 0);
    }
    const float bv = h2b[nc + ln16];
    #pragma unroll
    for (int r = 0; r < 4; ++r) {
      const int rr = quad * 4 + r;
      if (rr < 8) h2s[rr][nc + ln16] = (_Float16)gelu_f(a4[r] + bv);
    }
  }
  __syncthreads();

  // h3: out[sample] = h2s[s][:64] . h3w + h3b  (32 threads/sample)
  {
    const int s = tid >> 5, u = tid & 31;
    float v = (float)h2s[s][2 * u] * h3w[2 * u] +
              (float)h2s[s][2 * u + 1] * h3w[2 * u + 1];
    v += __shfl_xor(v, 1); v += __shfl_xor(v, 2); v += __shfl_xor(v, 4);
    v += __shfl_xor(v, 8); v += __shfl_xor(v, 16);
    if (u == 0) out[blockIdx.x * 8 + s] = v + h3b[0];
  }
}

// ---------------------------------------------------------------------------
extern "C" void kernel_launch(void* const* d_in, const int* in_sizes, int n_in,
                              void* d_out, int out_size, void* d_ws, size_t ws_size,
                              hipStream_t stream) {
  (void)in_sizes; (void)n_in; (void)out_size; (void)ws_size;
  const float* emb       = (const float*)d_in[0];
  const float* in_ln_w   = (const float*)d_in[1];
  const float* in_ln_b   = (const float*)d_in[2];
  const float* in_proj_w = (const float*)d_in[3];
  const float* in_proj_b = (const float*)d_in[4];
  const float* qkv_w     = (const float*)d_in[5];
  const float* qkv_b     = (const float*)d_in[6];
  const float* aow       = (const float*)d_in[7];
  const float* aob       = (const float*)d_in[8];
  const float* ln1w      = (const float*)d_in[9];
  const float* ln1b      = (const float*)d_in[10];
  const float* ln2w      = (const float*)d_in[11];
  const float* ln2b      = (const float*)d_in[12];
  const float* ff1w      = (const float*)d_in[13];
  const float* ff1b      = (const float*)d_in[14];
  const float* ff2w      = (const float*)d_in[15];
  const float* ff2b      = (const float*)d_in[16];
  const float* hlnw      = (const float*)d_in[17];
  const float* hlnb      = (const float*)d_in[18];
  const float* h1w       = (const float*)d_in[19];
  const float* h1b       = (const float*)d_in[20];
  const float* h2w       = (const float*)d_in[21];
  const float* h2b       = (const float*)d_in[22];
  const float* h3w       = (const float*)d_in[23];
  const float* h3b       = (const float*)d_in[24];
  float* out = (float*)d_out;

  float* ws = (float*)d_ws;
  size_t off = 0;
  float* x   = ws + off; off += (size_t)MTOK * D_;   // fp32 residual stream
  float* stD = ws + off; off += (size_t)MTOK * 2;    // per-token LN stats
  float* c1  = ws + off; off += 192;                 // in_proj LN-fold consts
  float* c2  = ws + off; off += 192;
  // fp16 weight pack region
  _Float16* wh = (_Float16*)(ws + off);
  _Float16* w_inproj = wh;                       // 192*1152  = 221184
  _Float16* w_qkv    = w_inproj + 221184;        // 2*576*192 = 221184
  _Float16* w_ao     = w_qkv    + 221184;        // 2*192*192 =  73728
  _Float16* w_ff1    = w_ao     + 73728;         // 2*768*192 = 294912
  _Float16* w_ff2    = w_ff1    + 294912;        // 2*192*768 = 294912
  _Float16* w_h1     = w_ff2    + 294912;        // 256*192   =  49152
  _Float16* w_h2     = w_h1     + 49152;         // 64*256    =  16384

  prep_inproj_w<<<48, 256, 0, stream>>>(in_proj_w, in_ln_w, in_ln_b, in_proj_b,
                                        w_inproj, c1, c2);
  cvt_f16_kernel<<<221184 / 2048, 256, 0, stream>>>(qkv_w, w_qkv);
  cvt_f16_kernel<<<73728  / 2048, 256, 0, stream>>>(aow, w_ao);
  cvt_f16_kernel<<<294912 / 2048, 256, 0, stream>>>(ff1w, w_ff1);
  cvt_f16_kernel<<<294912 / 2048, 256, 0, stream>>>(ff2w, w_ff2);
  cvt_f16_kernel<<<49152  / 2048, 256, 0, stream>>>(h1w, w_h1);
  cvt_f16_kernel<<<16384  / 2048, 256, 0, stream>>>(h2w, w_h2);

  inproj2_kernel<<<MTOK / 64, 256, 0, stream>>>(emb, w_inproj, c1, c2, x, stD);

  for (int i = 0; i < NL_; ++i) {
    layer_attn_kernel<<<MTOK / 32, 256, 0, stream>>>(
        x, w_qkv + (size_t)i * 110592, qkv_b + (size_t)i * 576,
        w_ao + (size_t)i * 36864, aob + (size_t)i * 192,
        ln1w + (size_t)i * 192, ln1b + (size_t)i * 192, stD);
    layer_ff_kernel<<<MTOK / 64, 256, 0, stream>>>(
        x, w_ff1 + (size_t)i * 147456, ff1b + (size_t)i * 768,
        w_ff2 + (size_t)i * 147456, ff2b + (size_t)i * 192,
        ln2w + (size_t)i * 192, ln2b + (size_t)i * 192, stD);
  }

  head_kernel<<<MTOK / 32, 256, 0, stream>>>(
      x, hlnw, hlnb, w_h1, h1b, w_h2, h2b, h3w, h3b, out);
}